// Round 1
// baseline (594.857 us; speedup 1.0000x reference)
//
#include <hip/hip_runtime.h>
#include <math.h>

#define D_MODEL 768
#define D_INNER 1536
#define L_SEQ   1024
#define DT_RANK 48
#define D_STATE 64
#define NXZ     3072   // 2*D_INNER
#define NDBL    176    // DT_RANK + 2*D_STATE

// ---------------- LayerNorm (one block per row) ----------------
__global__ __launch_bounds__(256) void ln_kernel(const float* __restrict__ x,
        const float* __restrict__ g, const float* __restrict__ b,
        float* __restrict__ xn) {
    int row = blockIdx.x;
    const float* xr = x + row * D_MODEL;
    float v[3];
    float s = 0.f, s2 = 0.f;
    #pragma unroll
    for (int i = 0; i < 3; i++) {
        v[i] = xr[threadIdx.x + i * 256];
        s += v[i]; s2 += v[i] * v[i];
    }
    #pragma unroll
    for (int o = 32; o > 0; o >>= 1) {
        s  += __shfl_xor(s,  o, 64);
        s2 += __shfl_xor(s2, o, 64);
    }
    __shared__ float red[2][4];
    int wid = threadIdx.x >> 6;
    if ((threadIdx.x & 63) == 0) { red[0][wid] = s; red[1][wid] = s2; }
    __syncthreads();
    s  = red[0][0] + red[0][1] + red[0][2] + red[0][3];
    s2 = red[1][0] + red[1][1] + red[1][2] + red[1][3];
    float mu  = s * (1.f / D_MODEL);
    float var = s2 * (1.f / D_MODEL) - mu * mu;
    float r   = rsqrtf(var + 1e-5f);
    #pragma unroll
    for (int i = 0; i < 3; i++) {
        int c = threadIdx.x + i * 256;
        xn[row * D_MODEL + c] = (v[i] - mu) * r * g[c] + b[c];
    }
}

// ---------------- fp32 GEMM: C[M,N] = A[M,K(lda)] * B[K,N(ldb)] ----------------
// BM=BN=64, BK=16, 4x4 per thread, 256 threads. M%64==0, K%16==0 assumed; N guarded.
// EPI==1: softplus(acc + bias[col])
template<int EPI>
__global__ __launch_bounds__(256) void gemm64(
        const float* __restrict__ A, int lda,
        const float* __restrict__ B, int ldb,
        float* __restrict__ C, int ldc,
        int N, int K, const float* __restrict__ bias) {
    __shared__ float As[16][68];   // transposed A tile, pad keeps 16B alignment, <=2-way banks
    __shared__ float Bs[16][68];
    int m0 = blockIdx.x * 64;
    int n0 = blockIdx.y * 64;
    int tid = threadIdx.x;
    int tx = tid & 15, ty = tid >> 4;
    int arow = tid >> 2, acol = (tid & 3) * 4;   // A tile: 64 rows x 16 cols, 1 float4/thread
    int brow = tid >> 4, bcol = (tid & 15) * 4;  // B tile: 16 rows x 64 cols, 1 float4/thread

    float acc[4][4] = {};
    int nk = K / 16;
    for (int kt = 0; kt < nk; kt++) {
        int k0 = kt * 16;
        float4 av = *(const float4*)(A + (size_t)(m0 + arow) * lda + k0 + acol);
        float4 bv;
        if (n0 + bcol + 4 <= N) {
            bv = *(const float4*)(B + (size_t)(k0 + brow) * ldb + n0 + bcol);
        } else {
            float tmp[4] = {0.f, 0.f, 0.f, 0.f};
            #pragma unroll
            for (int j = 0; j < 4; j++)
                if (n0 + bcol + j < N) tmp[j] = B[(size_t)(k0 + brow) * ldb + n0 + bcol + j];
            bv = make_float4(tmp[0], tmp[1], tmp[2], tmp[3]);
        }
        __syncthreads();
        As[acol + 0][arow] = av.x;
        As[acol + 1][arow] = av.y;
        As[acol + 2][arow] = av.z;
        As[acol + 3][arow] = av.w;
        *(float4*)&Bs[brow][bcol] = bv;
        __syncthreads();
        #pragma unroll
        for (int k = 0; k < 16; k++) {
            float4 a4 = *(const float4*)&As[k][ty * 4];
            float4 b4 = *(const float4*)&Bs[k][tx * 4];
            float ar[4] = {a4.x, a4.y, a4.z, a4.w};
            float br[4] = {b4.x, b4.y, b4.z, b4.w};
            #pragma unroll
            for (int i = 0; i < 4; i++)
                #pragma unroll
                for (int j = 0; j < 4; j++)
                    acc[i][j] = fmaf(ar[i], br[j], acc[i][j]);
        }
    }
    #pragma unroll
    for (int i = 0; i < 4; i++) {
        int row = m0 + ty * 4 + i;
        #pragma unroll
        for (int j = 0; j < 4; j++) {
            int col = n0 + tx * 4 + j;
            if (col < N) {
                float v = acc[i][j];
                if (EPI == 1) {
                    float u = v + bias[col];
                    v = (u > 15.f) ? u : log1pf(__expf(u));
                }
                C[(size_t)row * ldc + col] = v;
            }
        }
    }
}

// ---------------- causal depthwise conv(4) + SiLU ----------------
__global__ __launch_bounds__(256) void conv_silu_kernel(const float* __restrict__ xz,
        const float* __restrict__ cw, const float* __restrict__ cb,
        float* __restrict__ xc) {
    int idx = blockIdx.x * 256 + threadIdx.x;   // t*D_INNER + d
    int t = idx / D_INNER;
    int d = idx - t * D_INNER;
    float acc = cb[d];
    #pragma unroll
    for (int k = 0; k < 4; k++) {
        int ts = t - 3 + k;
        if (ts >= 0) acc = fmaf(xz[(size_t)ts * NXZ + d], cw[d * 4 + k], acc);
    }
    xc[idx] = acc / (1.f + __expf(-acc));   // silu
}

// ---------------- selective scan: wave per channel, lane = state ----------------
// Fused epilogue: y = (sum_n h*C + xc*D_skip) * silu(z)
__global__ __launch_bounds__(256) void scan_kernel(
        const float* __restrict__ dt, const float* __restrict__ xc,
        const float* __restrict__ dbl, const float* __restrict__ A_log,
        const float* __restrict__ D_skip, const float* __restrict__ xz,
        float* __restrict__ y) {
    int wid  = threadIdx.x >> 6;
    int lane = threadIdx.x & 63;
    int d = blockIdx.x * 4 + wid;
    float A_dn = -__expf(A_log[d * D_STATE + lane]);
    float Dv = D_skip[d];
    float h = 0.f;
    for (int t0 = 0; t0 < L_SEQ; t0 += 8) {
        float p[8], xcs[8], dts[8];
        #pragma unroll
        for (int i = 0; i < 8; i++) {
            int t = t0 + i;
            dts[i] = dt[(size_t)t * D_INNER + d];   // wave-broadcast load
            xcs[i] = xc[(size_t)t * D_INNER + d];
        }
        #pragma unroll
        for (int i = 0; i < 8; i++) {
            int t = t0 + i;
            float Bv = dbl[(size_t)t * NDBL + DT_RANK + lane];
            float Cv = dbl[(size_t)t * NDBL + DT_RANK + D_STATE + lane];
            float dA = __expf(dts[i] * A_dn);
            h = fmaf(dA, h, dts[i] * Bv * xcs[i]);
            p[i] = h * Cv;
        }
        // 8 independent 64-lane butterflies, pipelined
        #pragma unroll
        for (int s = 1; s < 64; s <<= 1) {
            #pragma unroll
            for (int i = 0; i < 8; i++) p[i] += __shfl_xor(p[i], s, 64);
        }
        if (lane == 0) {
            #pragma unroll
            for (int i = 0; i < 8; i++) {
                int t = t0 + i;
                float zv = xz[(size_t)t * NXZ + D_INNER + d];
                float yv = p[i] + xcs[i] * Dv;
                y[(size_t)t * D_INNER + d] = yv * (zv / (1.f + __expf(-zv)));
            }
        }
    }
}

// ---------------- host ----------------
extern "C" void kernel_launch(void* const* d_in, const int* in_sizes, int n_in,
                              void* d_out, int out_size, void* d_ws, size_t ws_size,
                              hipStream_t stream) {
    const float* x      = (const float*)d_in[0];
    const float* ln_g   = (const float*)d_in[1];
    const float* ln_b   = (const float*)d_in[2];
    const float* W_in   = (const float*)d_in[3];
    const float* conv_w = (const float*)d_in[4];
    const float* conv_b = (const float*)d_in[5];
    const float* W_x    = (const float*)d_in[6];
    const float* W_dt   = (const float*)d_in[7];
    const float* b_dt   = (const float*)d_in[8];
    const float* A_log  = (const float*)d_in[9];
    const float* D_skip = (const float*)d_in[10];
    const float* W_out  = (const float*)d_in[11];

    float* ws  = (float*)d_ws;
    float* xn  = ws;                 // 1024*768
    float* xz  = ws + 786432;        // 1024*3072
    float* xc  = ws + 3932160;       // 1024*1536
    float* dbl = ws + 5505024;       // 1024*176
    float* dtb = ws + 5685248;       // 1024*1536
    float* yv  = ws + 7258112;       // 1024*1536  (total 8830976 floats = 35.3 MB)

    ln_kernel<<<L_SEQ, 256, 0, stream>>>(x, ln_g, ln_b, xn);
    // xz = xn @ W_in  (1024 x 3072, K=768)
    gemm64<0><<<dim3(16, 48), 256, 0, stream>>>(xn, D_MODEL, W_in, NXZ, xz, NXZ, NXZ, D_MODEL, nullptr);
    // xc = silu(depthwise_conv(xi) + b)
    conv_silu_kernel<<<(L_SEQ * D_INNER) / 256, 256, 0, stream>>>(xz, conv_w, conv_b, xc);
    // dbl = xc @ W_x  (1024 x 176, K=1536)
    gemm64<0><<<dim3(16, 3), 256, 0, stream>>>(xc, D_INNER, W_x, NDBL, dbl, NDBL, NDBL, D_INNER, nullptr);
    // dt = softplus(dt_raw @ W_dt + b_dt)  (1024 x 1536, K=48, lda=176)
    gemm64<1><<<dim3(16, 24), 256, 0, stream>>>(dbl, NDBL, W_dt, D_INNER, dtb, D_INNER, D_INNER, DT_RANK, b_dt);
    // selective scan + gating
    scan_kernel<<<D_INNER / 4, 256, 0, stream>>>(dtb, xc, dbl, A_log, D_skip, xz, yv);
    // out = y @ W_out  (1024 x 768, K=1536)
    gemm64<0><<<dim3(16, 12), 256, 0, stream>>>(yv, D_INNER, W_out, D_MODEL, (float*)d_out, D_MODEL, D_MODEL, D_INNER, nullptr);
}

// Round 2
// 475.414 us; speedup vs baseline: 1.2512x; 1.2512x over previous
//
#include <hip/hip_runtime.h>
#include <math.h>

#define D_MODEL 768
#define D_INNER 1536
#define L_SEQ   1024
#define DT_RANK 48
#define D_STATE 64
#define NXZ     3072   // 2*D_INNER
#define NDBL    176    // DT_RANK + 2*D_STATE
#define NCHUNK  16
#define QCH     64     // chunk length

// ---------------- LayerNorm (one block per row) ----------------
__global__ __launch_bounds__(256) void ln_kernel(const float* __restrict__ x,
        const float* __restrict__ g, const float* __restrict__ b,
        float* __restrict__ xn) {
    int row = blockIdx.x;
    const float* xr = x + row * D_MODEL;
    float v[3];
    float s = 0.f, s2 = 0.f;
    #pragma unroll
    for (int i = 0; i < 3; i++) {
        v[i] = xr[threadIdx.x + i * 256];
        s += v[i]; s2 += v[i] * v[i];
    }
    #pragma unroll
    for (int o = 32; o > 0; o >>= 1) {
        s  += __shfl_xor(s,  o, 64);
        s2 += __shfl_xor(s2, o, 64);
    }
    __shared__ float red[2][4];
    int wid = threadIdx.x >> 6;
    if ((threadIdx.x & 63) == 0) { red[0][wid] = s; red[1][wid] = s2; }
    __syncthreads();
    s  = red[0][0] + red[0][1] + red[0][2] + red[0][3];
    s2 = red[1][0] + red[1][1] + red[1][2] + red[1][3];
    float mu  = s * (1.f / D_MODEL);
    float var = s2 * (1.f / D_MODEL) - mu * mu;
    float r   = rsqrtf(var + 1e-5f);
    #pragma unroll
    for (int i = 0; i < 3; i++) {
        int c = threadIdx.x + i * 256;
        xn[row * D_MODEL + c] = (v[i] - mu) * r * g[c] + b[c];
    }
}

// ---------------- fp32 GEMM: C[M,N] = A[M,K(lda)] * B[K,N(ldb)] ----------------
template<int EPI>
__global__ __launch_bounds__(256) void gemm64(
        const float* __restrict__ A, int lda,
        const float* __restrict__ B, int ldb,
        float* __restrict__ C, int ldc,
        int N, int K, const float* __restrict__ bias) {
    __shared__ float As[16][68];
    __shared__ float Bs[16][68];
    int m0 = blockIdx.x * 64;
    int n0 = blockIdx.y * 64;
    int tid = threadIdx.x;
    int tx = tid & 15, ty = tid >> 4;
    int arow = tid >> 2, acol = (tid & 3) * 4;
    int brow = tid >> 4, bcol = (tid & 15) * 4;

    float acc[4][4] = {};
    int nk = K / 16;
    for (int kt = 0; kt < nk; kt++) {
        int k0 = kt * 16;
        float4 av = *(const float4*)(A + (size_t)(m0 + arow) * lda + k0 + acol);
        float4 bv;
        if (n0 + bcol + 4 <= N) {
            bv = *(const float4*)(B + (size_t)(k0 + brow) * ldb + n0 + bcol);
        } else {
            float tmp[4] = {0.f, 0.f, 0.f, 0.f};
            #pragma unroll
            for (int j = 0; j < 4; j++)
                if (n0 + bcol + j < N) tmp[j] = B[(size_t)(k0 + brow) * ldb + n0 + bcol + j];
            bv = make_float4(tmp[0], tmp[1], tmp[2], tmp[3]);
        }
        __syncthreads();
        As[acol + 0][arow] = av.x;
        As[acol + 1][arow] = av.y;
        As[acol + 2][arow] = av.z;
        As[acol + 3][arow] = av.w;
        *(float4*)&Bs[brow][bcol] = bv;
        __syncthreads();
        #pragma unroll
        for (int k = 0; k < 16; k++) {
            float4 a4 = *(const float4*)&As[k][ty * 4];
            float4 b4 = *(const float4*)&Bs[k][tx * 4];
            float ar[4] = {a4.x, a4.y, a4.z, a4.w};
            float br[4] = {b4.x, b4.y, b4.z, b4.w};
            #pragma unroll
            for (int i = 0; i < 4; i++)
                #pragma unroll
                for (int j = 0; j < 4; j++)
                    acc[i][j] = fmaf(ar[i], br[j], acc[i][j]);
        }
    }
    #pragma unroll
    for (int i = 0; i < 4; i++) {
        int row = m0 + ty * 4 + i;
        #pragma unroll
        for (int j = 0; j < 4; j++) {
            int col = n0 + tx * 4 + j;
            if (col < N) {
                float v = acc[i][j];
                if (EPI == 1) {
                    float u = v + bias[col];
                    v = (u > 15.f) ? u : log1pf(__expf(u));
                }
                C[(size_t)row * ldc + col] = v;
            }
        }
    }
}

// ---------------- causal depthwise conv(4) + SiLU ----------------
__global__ __launch_bounds__(256) void conv_silu_kernel(const float* __restrict__ xz,
        const float* __restrict__ cw, const float* __restrict__ cb,
        float* __restrict__ xc) {
    int idx = blockIdx.x * 256 + threadIdx.x;
    int t = idx / D_INNER;
    int d = idx - t * D_INNER;
    float acc = cb[d];
    #pragma unroll
    for (int k = 0; k < 4; k++) {
        int ts = t - 3 + k;
        if (ts >= 0) acc = fmaf(xz[(size_t)ts * NXZ + d], cw[d * 4 + k], acc);
    }
    xc[idx] = acc / (1.f + __expf(-acc));
}

// ================= chunked selective scan =================
// S1: per (d,chunk) wave, lane=n. Local scan with h0=0; emit final local h and
//     chunk decay P = exp(A_n * sum(dt over chunk)).  Layout [chunk][d][n].
__global__ __launch_bounds__(256) void scan_s1(
        const float* __restrict__ dtb, const float* __restrict__ xc,
        const float* __restrict__ dbl, const float* __restrict__ A_log,
        float* __restrict__ hloc, float* __restrict__ Pfac) {
    int wid = threadIdx.x >> 6, lane = threadIdx.x & 63;
    int d = blockIdx.x * 4 + wid;
    int c = blockIdx.y;
    float An = -__expf(A_log[d * D_STATE + lane]);
    float h = 0.f, sdt = 0.f;
    int tbase = c * QCH;
    #pragma unroll 8
    for (int i = 0; i < QCH; i++) {
        int t = tbase + i;
        float dtv = dtb[(size_t)t * D_INNER + d];
        float xcv = xc[(size_t)t * D_INNER + d];
        float Bv  = dbl[(size_t)t * NDBL + DT_RANK + lane];
        float a = __expf(dtv * An);
        h = fmaf(a, h, dtv * Bv * xcv);
        sdt += dtv;
    }
    int o = (c * D_INNER + d) * D_STATE + lane;
    hloc[o] = h;
    Pfac[o] = __expf(sdt * An);
}

// S2: per (d,n) thread: serial combine over 16 chunks; emit H entering each chunk.
__global__ __launch_bounds__(256) void scan_s2(
        const float* __restrict__ hloc, const float* __restrict__ Pfac,
        float* __restrict__ Hinit) {
    int idx = blockIdx.x * 256 + threadIdx.x;   // d*64 + n
    float H = 0.f;
    #pragma unroll
    for (int c = 0; c < NCHUNK; c++) {
        int o = c * (D_INNER * D_STATE) + idx;
        Hinit[o] = H;
        H = fmaf(Pfac[o], H, hloc[o]);
    }
}

// S3: per (d,chunk) wave, lane=n. Re-run local scan seeded with Hinit; per 8
// timesteps reduce 8 independent 64-lane sums with a 10-shuffle fold network;
// fused epilogue y = (sum + xc*D)*silu(z).
__global__ __launch_bounds__(256) void scan_s3(
        const float* __restrict__ dtb, const float* __restrict__ xc,
        const float* __restrict__ dbl, const float* __restrict__ A_log,
        const float* __restrict__ Hinit, const float* __restrict__ D_skip,
        const float* __restrict__ xz, float* __restrict__ y) {
    int wid = threadIdx.x >> 6, lane = threadIdx.x & 63;
    int d = blockIdx.x * 4 + wid;
    int c = blockIdx.y;
    float An = -__expf(A_log[d * D_STATE + lane]);
    float Dv = D_skip[d];
    float h = Hinit[(c * D_INNER + d) * D_STATE + lane];
    int li = lane & 7;
    int tbase = c * QCH;
    for (int t0 = tbase; t0 < tbase + QCH; t0 += 8) {
        float p[8], dts[8], xcs[8];
        #pragma unroll
        for (int i = 0; i < 8; i++) {
            dts[i] = dtb[(size_t)(t0 + i) * D_INNER + d];
            xcs[i] = xc[(size_t)(t0 + i) * D_INNER + d];
        }
        #pragma unroll
        for (int i = 0; i < 8; i++) {
            int t = t0 + i;
            float Bv = dbl[(size_t)t * NDBL + DT_RANK + lane];
            float Cv = dbl[(size_t)t * NDBL + DT_RANK + D_STATE + lane];
            float a = __expf(dts[i] * An);
            h = fmaf(a, h, dts[i] * Bv * xcs[i]);
            p[i] = h * Cv;
        }
        // fold network: after 3 fold levels + 3 butterfly rounds, lane holds
        // the full 64-lane sum for value index (lane & 7).
        float q[4];
        #pragma unroll
        for (int i = 0; i < 4; i++) {
            bool b = (lane & 1) != 0;
            float send = b ? p[2*i] : p[2*i+1];
            float keep = b ? p[2*i+1] : p[2*i];
            q[i] = keep + __shfl_xor(send, 1, 64);
        }
        float r[2];
        #pragma unroll
        for (int i = 0; i < 2; i++) {
            bool b = (lane & 2) != 0;
            float send = b ? q[2*i] : q[2*i+1];
            float keep = b ? q[2*i+1] : q[2*i];
            r[i] = keep + __shfl_xor(send, 2, 64);
        }
        float s;
        {
            bool b = (lane & 4) != 0;
            float send = b ? r[0] : r[1];
            float keep = b ? r[1] : r[0];
            s = keep + __shfl_xor(send, 4, 64);
        }
        s += __shfl_xor(s, 8, 64);
        s += __shfl_xor(s, 16, 64);
        s += __shfl_xor(s, 32, 64);
        if (lane < 8) {
            int t = t0 + li;
            float xcv = xc[(size_t)t * D_INNER + d];
            float zv  = xz[(size_t)t * NXZ + D_INNER + d];
            float yv  = s + xcv * Dv;
            y[(size_t)t * D_INNER + d] = yv * (zv / (1.f + __expf(-zv)));
        }
    }
}

// ---------------- host ----------------
extern "C" void kernel_launch(void* const* d_in, const int* in_sizes, int n_in,
                              void* d_out, int out_size, void* d_ws, size_t ws_size,
                              hipStream_t stream) {
    const float* x      = (const float*)d_in[0];
    const float* ln_g   = (const float*)d_in[1];
    const float* ln_b   = (const float*)d_in[2];
    const float* W_in   = (const float*)d_in[3];
    const float* conv_w = (const float*)d_in[4];
    const float* conv_b = (const float*)d_in[5];
    const float* W_x    = (const float*)d_in[6];
    const float* W_dt   = (const float*)d_in[7];
    const float* b_dt   = (const float*)d_in[8];
    const float* A_log  = (const float*)d_in[9];
    const float* D_skip = (const float*)d_in[10];
    const float* W_out  = (const float*)d_in[11];

    float* ws   = (float*)d_ws;
    float* xn   = ws;                  // 1024*768   = 786432
    float* xz   = ws + 786432;         // 1024*3072  = 3145728
    float* xc   = ws + 3932160;        // 1024*1536  = 1572864
    float* dbl  = ws + 5505024;        // 1024*176   = 180224
    float* dtb  = ws + 5685248;        // 1024*1536  = 1572864
    float* yv   = ws + 7258112;        // 1024*1536  = 1572864
    float* hloc = ws + 8830976;        // 16*1536*64 = 1572864
    float* Pfac = ws + 10403840;       // 16*1536*64 = 1572864
    float* Hini = ws + 11976704;       // 16*1536*64 = 1572864  (end 13549568 = 54.2 MB)

    ln_kernel<<<L_SEQ, 256, 0, stream>>>(x, ln_g, ln_b, xn);
    gemm64<0><<<dim3(16, 48), 256, 0, stream>>>(xn, D_MODEL, W_in, NXZ, xz, NXZ, NXZ, D_MODEL, nullptr);
    conv_silu_kernel<<<(L_SEQ * D_INNER) / 256, 256, 0, stream>>>(xz, conv_w, conv_b, xc);
    gemm64<0><<<dim3(16, 3), 256, 0, stream>>>(xc, D_INNER, W_x, NDBL, dbl, NDBL, NDBL, D_INNER, nullptr);
    gemm64<1><<<dim3(16, 24), 256, 0, stream>>>(dbl, NDBL, W_dt, D_INNER, dtb, D_INNER, D_INNER, DT_RANK, b_dt);
    scan_s1<<<dim3(D_INNER / 4, NCHUNK), 256, 0, stream>>>(dtb, xc, dbl, A_log, hloc, Pfac);
    scan_s2<<<(D_INNER * D_STATE) / 256, 256, 0, stream>>>(hloc, Pfac, Hini);
    scan_s3<<<dim3(D_INNER / 4, NCHUNK), 256, 0, stream>>>(dtb, xc, dbl, A_log, Hini, D_skip, xz, yv);
    gemm64<0><<<dim3(16, 12), 256, 0, stream>>>(yv, D_INNER, W_out, D_MODEL, (float*)d_out, D_MODEL, D_MODEL, D_INNER, nullptr);
}

// Round 3
// 386.241 us; speedup vs baseline: 1.5401x; 1.2309x over previous
//
#include <hip/hip_runtime.h>
#include <math.h>

#define D_MODEL 768
#define D_INNER 1536
#define L_SEQ   1024
#define DT_RANK 48
#define D_STATE 64
#define NXZ     3072   // 2*D_INNER
#define NDBL    176    // DT_RANK + 2*D_STATE
#define NCHUNK  16
#define QCH     64     // chunk length

// ---------------- LayerNorm (one block per row) ----------------
__global__ __launch_bounds__(256) void ln_kernel(const float* __restrict__ x,
        const float* __restrict__ g, const float* __restrict__ b,
        float* __restrict__ xn) {
    int row = blockIdx.x;
    const float* xr = x + row * D_MODEL;
    float v[3];
    float s = 0.f, s2 = 0.f;
    #pragma unroll
    for (int i = 0; i < 3; i++) {
        v[i] = xr[threadIdx.x + i * 256];
        s += v[i]; s2 += v[i] * v[i];
    }
    #pragma unroll
    for (int o = 32; o > 0; o >>= 1) {
        s  += __shfl_xor(s,  o, 64);
        s2 += __shfl_xor(s2, o, 64);
    }
    __shared__ float red[2][4];
    int wid = threadIdx.x >> 6;
    if ((threadIdx.x & 63) == 0) { red[0][wid] = s; red[1][wid] = s2; }
    __syncthreads();
    s  = red[0][0] + red[0][1] + red[0][2] + red[0][3];
    s2 = red[1][0] + red[1][1] + red[1][2] + red[1][3];
    float mu  = s * (1.f / D_MODEL);
    float var = s2 * (1.f / D_MODEL) - mu * mu;
    float r   = rsqrtf(var + 1e-5f);
    #pragma unroll
    for (int i = 0; i < 3; i++) {
        int c = threadIdx.x + i * 256;
        xn[row * D_MODEL + c] = (v[i] - mu) * r * g[c] + b[c];
    }
}

// ---------------- fp32 GEMM: C[M,N] (+)= A[M,K(lda)] * B[K,N(ldb)] ----------------
// BM=BN=64, BK=16, 4x4 per thread, 256 threads. Register prefetch of tile k+1
// before the inner product of tile k hides global latency behind the FMA loop.
// blockIdx.z = split-K slice (K assumed divisible by 16*gridDim.z).
// EPI==1: softplus(acc + bias[col]) store.  ATOMIC==1: atomicAdd into C.
template<int EPI, int ATOMIC>
__global__ __launch_bounds__(256) void gemm64(
        const float* __restrict__ A, int lda,
        const float* __restrict__ B, int ldb,
        float* __restrict__ C, int ldc,
        int N, int K, const float* __restrict__ bias) {
    __shared__ float As[16][68];
    __shared__ float Bs[16][68];
    int m0 = blockIdx.x * 64;
    int n0 = blockIdx.y * 64;
    int tid = threadIdx.x;
    int tx = tid & 15, ty = tid >> 4;
    int arow = tid >> 2, acol = (tid & 3) * 4;
    int brow = tid >> 4, bcol = (tid & 15) * 4;

    int nk = K / 16 / gridDim.z;
    int kbase = blockIdx.z * nk * 16;

    const float* Aptr = A + (size_t)(m0 + arow) * lda + kbase + acol;
    const float* Bptr = B + (size_t)kbase * ldb + (size_t)brow * ldb;

    auto loadB = [&](int kt) -> float4 {
        const float* bp = Bptr + (size_t)kt * 16 * ldb;
        if (n0 + bcol + 4 <= N) {
            return *(const float4*)(bp + n0 + bcol);
        } else {
            float tmp[4] = {0.f, 0.f, 0.f, 0.f};
            #pragma unroll
            for (int j = 0; j < 4; j++)
                if (n0 + bcol + j < N) tmp[j] = bp[n0 + bcol + j];
            return make_float4(tmp[0], tmp[1], tmp[2], tmp[3]);
        }
    };

    float acc[4][4] = {};
    float4 av = *(const float4*)(Aptr);
    float4 bv = loadB(0);

    for (int kt = 0; kt < nk; kt++) {
        __syncthreads();               // previous inner loop done with LDS
        As[acol + 0][arow] = av.x;
        As[acol + 1][arow] = av.y;
        As[acol + 2][arow] = av.z;
        As[acol + 3][arow] = av.w;
        *(float4*)&Bs[brow][bcol] = bv;
        __syncthreads();
        if (kt + 1 < nk) {             // prefetch next tile; latency hides under FMAs
            av = *(const float4*)(Aptr + (kt + 1) * 16);
            bv = loadB(kt + 1);
        }
        #pragma unroll
        for (int k = 0; k < 16; k++) {
            float4 a4 = *(const float4*)&As[k][ty * 4];
            float4 b4 = *(const float4*)&Bs[k][tx * 4];
            float ar[4] = {a4.x, a4.y, a4.z, a4.w};
            float br[4] = {b4.x, b4.y, b4.z, b4.w};
            #pragma unroll
            for (int i = 0; i < 4; i++)
                #pragma unroll
                for (int j = 0; j < 4; j++)
                    acc[i][j] = fmaf(ar[i], br[j], acc[i][j]);
        }
    }
    #pragma unroll
    for (int i = 0; i < 4; i++) {
        int row = m0 + ty * 4 + i;
        #pragma unroll
        for (int j = 0; j < 4; j++) {
            int col = n0 + tx * 4 + j;
            if (col < N) {
                float v = acc[i][j];
                if (ATOMIC == 1) {
                    atomicAdd(&C[(size_t)row * ldc + col], v);
                } else {
                    if (EPI == 1) {
                        float u = v + bias[col];
                        v = (u > 15.f) ? u : log1pf(__expf(u));
                    }
                    C[(size_t)row * ldc + col] = v;
                }
            }
        }
    }
}

// ---------------- causal depthwise conv(4) + SiLU ----------------
__global__ __launch_bounds__(256) void conv_silu_kernel(const float* __restrict__ xz,
        const float* __restrict__ cw, const float* __restrict__ cb,
        float* __restrict__ xc) {
    int idx = blockIdx.x * 256 + threadIdx.x;
    int t = idx / D_INNER;
    int d = idx - t * D_INNER;
    float acc = cb[d];
    #pragma unroll
    for (int k = 0; k < 4; k++) {
        int ts = t - 3 + k;
        if (ts >= 0) acc = fmaf(xz[(size_t)ts * NXZ + d], cw[d * 4 + k], acc);
    }
    xc[idx] = acc / (1.f + __expf(-acc));
}

// ================= chunked selective scan =================
__global__ __launch_bounds__(256) void scan_s1(
        const float* __restrict__ dtb, const float* __restrict__ xc,
        const float* __restrict__ dbl, const float* __restrict__ A_log,
        float* __restrict__ hloc, float* __restrict__ Pfac) {
    int wid = threadIdx.x >> 6, lane = threadIdx.x & 63;
    int d = blockIdx.x * 4 + wid;
    int c = blockIdx.y;
    float An = -__expf(A_log[d * D_STATE + lane]);
    float h = 0.f, sdt = 0.f;
    int tbase = c * QCH;
    #pragma unroll 8
    for (int i = 0; i < QCH; i++) {
        int t = tbase + i;
        float dtv = dtb[(size_t)t * D_INNER + d];
        float xcv = xc[(size_t)t * D_INNER + d];
        float Bv  = dbl[(size_t)t * NDBL + DT_RANK + lane];
        float a = __expf(dtv * An);
        h = fmaf(a, h, dtv * Bv * xcv);
        sdt += dtv;
    }
    int o = (c * D_INNER + d) * D_STATE + lane;
    hloc[o] = h;
    Pfac[o] = __expf(sdt * An);
}

__global__ __launch_bounds__(256) void scan_s2(
        const float* __restrict__ hloc, const float* __restrict__ Pfac,
        float* __restrict__ Hinit) {
    int idx = blockIdx.x * 256 + threadIdx.x;   // d*64 + n
    float H = 0.f;
    #pragma unroll
    for (int c = 0; c < NCHUNK; c++) {
        int o = c * (D_INNER * D_STATE) + idx;
        Hinit[o] = H;
        H = fmaf(Pfac[o], H, hloc[o]);
    }
}

__global__ __launch_bounds__(256) void scan_s3(
        const float* __restrict__ dtb, const float* __restrict__ xc,
        const float* __restrict__ dbl, const float* __restrict__ A_log,
        const float* __restrict__ Hinit, const float* __restrict__ D_skip,
        const float* __restrict__ xz, float* __restrict__ y) {
    int wid = threadIdx.x >> 6, lane = threadIdx.x & 63;
    int d = blockIdx.x * 4 + wid;
    int c = blockIdx.y;
    float An = -__expf(A_log[d * D_STATE + lane]);
    float Dv = D_skip[d];
    float h = Hinit[(c * D_INNER + d) * D_STATE + lane];
    int li = lane & 7;
    int tbase = c * QCH;
    for (int t0 = tbase; t0 < tbase + QCH; t0 += 8) {
        float p[8], dts[8], xcs[8];
        #pragma unroll
        for (int i = 0; i < 8; i++) {
            dts[i] = dtb[(size_t)(t0 + i) * D_INNER + d];
            xcs[i] = xc[(size_t)(t0 + i) * D_INNER + d];
        }
        #pragma unroll
        for (int i = 0; i < 8; i++) {
            int t = t0 + i;
            float Bv = dbl[(size_t)t * NDBL + DT_RANK + lane];
            float Cv = dbl[(size_t)t * NDBL + DT_RANK + D_STATE + lane];
            float a = __expf(dts[i] * An);
            h = fmaf(a, h, dts[i] * Bv * xcs[i]);
            p[i] = h * Cv;
        }
        float q[4];
        #pragma unroll
        for (int i = 0; i < 4; i++) {
            bool b = (lane & 1) != 0;
            float send = b ? p[2*i] : p[2*i+1];
            float keep = b ? p[2*i+1] : p[2*i];
            q[i] = keep + __shfl_xor(send, 1, 64);
        }
        float r[2];
        #pragma unroll
        for (int i = 0; i < 2; i++) {
            bool b = (lane & 2) != 0;
            float send = b ? q[2*i] : q[2*i+1];
            float keep = b ? q[2*i+1] : q[2*i];
            r[i] = keep + __shfl_xor(send, 2, 64);
        }
        float s;
        {
            bool b = (lane & 4) != 0;
            float send = b ? r[0] : r[1];
            float keep = b ? r[1] : r[0];
            s = keep + __shfl_xor(send, 4, 64);
        }
        s += __shfl_xor(s, 8, 64);
        s += __shfl_xor(s, 16, 64);
        s += __shfl_xor(s, 32, 64);
        if (lane < 8) {
            int t = t0 + li;
            float xcv = xc[(size_t)t * D_INNER + d];
            float zv  = xz[(size_t)t * NXZ + D_INNER + d];
            float yv  = s + xcv * Dv;
            y[(size_t)t * D_INNER + d] = yv * (zv / (1.f + __expf(-zv)));
        }
    }
}

// ---------------- host ----------------
extern "C" void kernel_launch(void* const* d_in, const int* in_sizes, int n_in,
                              void* d_out, int out_size, void* d_ws, size_t ws_size,
                              hipStream_t stream) {
    const float* x      = (const float*)d_in[0];
    const float* ln_g   = (const float*)d_in[1];
    const float* ln_b   = (const float*)d_in[2];
    const float* W_in   = (const float*)d_in[3];
    const float* conv_w = (const float*)d_in[4];
    const float* conv_b = (const float*)d_in[5];
    const float* W_x    = (const float*)d_in[6];
    const float* W_dt   = (const float*)d_in[7];
    const float* b_dt   = (const float*)d_in[8];
    const float* A_log  = (const float*)d_in[9];
    const float* D_skip = (const float*)d_in[10];
    const float* W_out  = (const float*)d_in[11];

    float* ws   = (float*)d_ws;
    float* xn   = ws;                  // 1024*768   = 786432
    float* xz   = ws + 786432;         // 1024*3072  = 3145728
    float* xc   = ws + 3932160;        // 1024*1536  = 1572864
    float* dbl  = ws + 5505024;        // 1024*176   = 180224
    float* dtb  = ws + 5685248;        // 1024*1536  = 1572864
    float* yv   = ws + 7258112;        // 1024*1536  = 1572864
    float* hloc = ws + 8830976;        // 16*1536*64 = 1572864
    float* Pfac = ws + 10403840;       // 16*1536*64 = 1572864
    float* Hini = ws + 11976704;       // 16*1536*64 = 1572864  (end 13549568 = 54.2 MB)

    // zero the split-K accumulation targets (capture-safe async memset)
    hipMemsetAsync(dbl, 0, (size_t)L_SEQ * NDBL * sizeof(float), stream);
    hipMemsetAsync(d_out, 0, (size_t)L_SEQ * D_MODEL * sizeof(float), stream);

    ln_kernel<<<L_SEQ, 256, 0, stream>>>(x, ln_g, ln_b, xn);
    // GEMM1: xz = xn @ W_in  (1024x3072, K=768) — 768 blocks, no split
    gemm64<0,0><<<dim3(16, 48, 1), 256, 0, stream>>>(xn, D_MODEL, W_in, NXZ, xz, NXZ, NXZ, D_MODEL, nullptr);
    conv_silu_kernel<<<(L_SEQ * D_INNER) / 256, 256, 0, stream>>>(xz, conv_w, conv_b, xc);
    // GEMM2: dbl += xc @ W_x  (1024x176, K=1536) — split-K x8 -> 384 blocks
    gemm64<0,1><<<dim3(16, 3, 8), 256, 0, stream>>>(xc, D_INNER, W_x, NDBL, dbl, NDBL, NDBL, D_INNER, nullptr);
    // GEMM3: dt = softplus(dt_raw @ W_dt + b_dt)  (1024x1536, K=48)
    gemm64<1,0><<<dim3(16, 24, 1), 256, 0, stream>>>(dbl, NDBL, W_dt, D_INNER, dtb, D_INNER, D_INNER, DT_RANK, b_dt);
    scan_s1<<<dim3(D_INNER / 4, NCHUNK), 256, 0, stream>>>(dtb, xc, dbl, A_log, hloc, Pfac);
    scan_s2<<<(D_INNER * D_STATE) / 256, 256, 0, stream>>>(hloc, Pfac, Hini);
    scan_s3<<<dim3(D_INNER / 4, NCHUNK), 256, 0, stream>>>(dtb, xc, dbl, A_log, Hini, D_skip, xz, yv);
    // GEMM4: out += y @ W_out  (1024x768, K=1536) — split-K x4 -> 768 blocks
    gemm64<0,1><<<dim3(16, 12, 4), 256, 0, stream>>>(yv, D_INNER, W_out, D_MODEL, (float*)d_out, D_MODEL, D_MODEL, D_INNER, nullptr);
}

// Round 4
// 365.347 us; speedup vs baseline: 1.6282x; 1.0572x over previous
//
#include <hip/hip_runtime.h>
#include <hip/hip_bf16.h>
#include <math.h>

#define D_MODEL 768
#define D_INNER 1536
#define L_SEQ   1024
#define DT_RANK 48
#define D_STATE 64
#define NXZ     3072   // 2*D_INNER
#define NDBL    176    // DT_RANK + 2*D_STATE
#define NCHUNK  16
#define QCH     64     // chunk length

typedef short  bfrag8 __attribute__((ext_vector_type(8)));
typedef float  f32x4  __attribute__((ext_vector_type(4)));

__device__ inline unsigned short bf_hi_u(float v) {
    __hip_bfloat16 h = __float2bfloat16(v);
    return *reinterpret_cast<unsigned short*>(&h);
}
__device__ inline float bf_to_f(unsigned short u) {
    __hip_bfloat16 h = *reinterpret_cast<__hip_bfloat16*>(&u);
    return __bfloat162float(h);
}

// ---------------- transpose + bf16(hi[,lo]) convert: src[R][C] fp32 -> dst[C][R] ----------------
template<int SPLIT>
__global__ __launch_bounds__(256) void tconv_kernel(const float* __restrict__ src, int R, int C,
        unsigned short* __restrict__ dhi, unsigned short* __restrict__ dlo) {
    __shared__ float tile[32][33];
    int tx = threadIdx.x & 31, ty = threadIdx.x >> 5;
    int c0 = blockIdx.x * 32, r0 = blockIdx.y * 32;
    #pragma unroll
    for (int i = 0; i < 4; i++)
        tile[ty + 8*i][tx] = src[(size_t)(r0 + ty + 8*i) * C + c0 + tx];
    __syncthreads();
    #pragma unroll
    for (int i = 0; i < 4; i++) {
        float v = tile[tx][ty + 8*i];
        size_t o = (size_t)(c0 + ty + 8*i) * R + r0 + tx;
        unsigned short h = bf_hi_u(v);
        dhi[o] = h;
        if (SPLIT) dlo[o] = bf_hi_u(v - bf_to_f(h));
    }
}

// ---------------- LayerNorm -> bf16 hi/lo planes ----------------
__global__ __launch_bounds__(256) void ln_kernel(const float* __restrict__ x,
        const float* __restrict__ g, const float* __restrict__ b,
        unsigned short* __restrict__ xn_hi, unsigned short* __restrict__ xn_lo) {
    int row = blockIdx.x;
    const float* xr = x + row * D_MODEL;
    float v[3];
    float s = 0.f, s2 = 0.f;
    #pragma unroll
    for (int i = 0; i < 3; i++) {
        v[i] = xr[threadIdx.x + i * 256];
        s += v[i]; s2 += v[i] * v[i];
    }
    #pragma unroll
    for (int o = 32; o > 0; o >>= 1) {
        s  += __shfl_xor(s,  o, 64);
        s2 += __shfl_xor(s2, o, 64);
    }
    __shared__ float red[2][4];
    int wid = threadIdx.x >> 6;
    if ((threadIdx.x & 63) == 0) { red[0][wid] = s; red[1][wid] = s2; }
    __syncthreads();
    s  = red[0][0] + red[0][1] + red[0][2] + red[0][3];
    s2 = red[1][0] + red[1][1] + red[1][2] + red[1][3];
    float mu  = s * (1.f / D_MODEL);
    float var = s2 * (1.f / D_MODEL) - mu * mu;
    float r   = rsqrtf(var + 1e-5f);
    #pragma unroll
    for (int i = 0; i < 3; i++) {
        int c = threadIdx.x + i * 256;
        float xv = (v[i] - mu) * r * g[c] + b[c];
        unsigned short h = bf_hi_u(xv);
        xn_hi[row * D_MODEL + c] = h;
        xn_lo[row * D_MODEL + c] = bf_hi_u(xv - bf_to_f(h));
    }
}

// ---------------- MFMA GEMM: C[M,N] (+)= A[M,K] * B^T[N,K] (bf16 planes) ----------------
// BM=BN=64, BK=32, 256 threads (4 waves, 2x2 of 32x32/wave, each 2x2 of 16x16 tiles).
// SPLIT3: A,B given as hi+lo planes; acc = hi*hi + hi*lo + lo*hi (~fp32 precision).
// ATOMIC: atomicAdd epilogue (split-K, blockIdx.z = slice).
template<int SPLIT3, int ATOMIC>
__global__ __launch_bounds__(256) void mgemm(
        const unsigned short* __restrict__ Ahi, const unsigned short* __restrict__ Alo,
        const unsigned short* __restrict__ Bhi, const unsigned short* __restrict__ Blo,
        float* __restrict__ C, int ldc, int K) {
    constexpr int NP = SPLIT3 ? 2 : 1;
    __shared__ unsigned short As[NP][64][40];   // [plane][m][k], +8 pad keeps 16B align, <=2-way banks
    __shared__ unsigned short Bs[NP][64][40];
    int tid = threadIdx.x;
    int m0 = blockIdx.x * 64, n0 = blockIdx.y * 64;
    int nk = K / 32 / gridDim.z;
    int kbase = blockIdx.z * nk * 32;
    int row = tid >> 2, kq = (tid & 3) * 8;

    const unsigned short* pa_hi = Ahi + (size_t)(m0 + row) * K + kbase + kq;
    const unsigned short* pb_hi = Bhi + (size_t)(n0 + row) * K + kbase + kq;
    const unsigned short* pa_lo = SPLIT3 ? (Alo + (size_t)(m0 + row) * K + kbase + kq) : nullptr;
    const unsigned short* pb_lo = SPLIT3 ? (Blo + (size_t)(n0 + row) * K + kbase + kq) : nullptr;

    uint4 va[NP], vb[NP];
    va[0] = *(const uint4*)pa_hi;
    vb[0] = *(const uint4*)pb_hi;
    if (SPLIT3) { va[1] = *(const uint4*)pa_lo; vb[1] = *(const uint4*)pb_lo; }

    int wv = tid >> 6, L = tid & 63;
    int wr = (wv >> 1) * 32, wc = (wv & 1) * 32;
    int lm = L & 15, koff = (L >> 4) * 8;

    f32x4 acc[2][2];
    #pragma unroll
    for (int i = 0; i < 2; i++)
        #pragma unroll
        for (int j = 0; j < 2; j++)
            #pragma unroll
            for (int r = 0; r < 4; r++) acc[i][j][r] = 0.f;

    for (int kt = 0; kt < nk; kt++) {
        __syncthreads();
        *(uint4*)&As[0][row][kq] = va[0];
        *(uint4*)&Bs[0][row][kq] = vb[0];
        if (SPLIT3) {
            *(uint4*)&As[1][row][kq] = va[1];
            *(uint4*)&Bs[1][row][kq] = vb[1];
        }
        __syncthreads();
        if (kt + 1 < nk) {   // prefetch next K-tile; hides under MFMAs
            va[0] = *(const uint4*)(pa_hi + (kt + 1) * 32);
            vb[0] = *(const uint4*)(pb_hi + (kt + 1) * 32);
            if (SPLIT3) {
                va[1] = *(const uint4*)(pa_lo + (kt + 1) * 32);
                vb[1] = *(const uint4*)(pb_lo + (kt + 1) * 32);
            }
        }
        bfrag8 fa[NP][2], fb[NP][2];
        #pragma unroll
        for (int mi = 0; mi < 2; mi++) {
            fa[0][mi] = *(const bfrag8*)&As[0][wr + mi * 16 + lm][koff];
            if (SPLIT3) fa[1][mi] = *(const bfrag8*)&As[1][wr + mi * 16 + lm][koff];
        }
        #pragma unroll
        for (int ni = 0; ni < 2; ni++) {
            fb[0][ni] = *(const bfrag8*)&Bs[0][wc + ni * 16 + lm][koff];
            if (SPLIT3) fb[1][ni] = *(const bfrag8*)&Bs[1][wc + ni * 16 + lm][koff];
        }
        #pragma unroll
        for (int mi = 0; mi < 2; mi++)
            #pragma unroll
            for (int ni = 0; ni < 2; ni++) {
                acc[mi][ni] = __builtin_amdgcn_mfma_f32_16x16x32_bf16(fa[0][mi], fb[0][ni], acc[mi][ni], 0, 0, 0);
                if (SPLIT3) {
                    acc[mi][ni] = __builtin_amdgcn_mfma_f32_16x16x32_bf16(fa[0][mi], fb[1][ni], acc[mi][ni], 0, 0, 0);
                    acc[mi][ni] = __builtin_amdgcn_mfma_f32_16x16x32_bf16(fa[1][mi], fb[0][ni], acc[mi][ni], 0, 0, 0);
                }
            }
    }
    // C/D layout: col = lane&15, row = (lane>>4)*4 + reg
    int rbase = (L >> 4) * 4, cbase = L & 15;
    #pragma unroll
    for (int mi = 0; mi < 2; mi++)
        #pragma unroll
        for (int ni = 0; ni < 2; ni++)
            #pragma unroll
            for (int r = 0; r < 4; r++) {
                int rr = m0 + wr + mi * 16 + rbase + r;
                int cc = n0 + wc + ni * 16 + cbase;
                if (ATOMIC) atomicAdd(&C[(size_t)rr * ldc + cc], acc[mi][ni][r]);
                else        C[(size_t)rr * ldc + cc] = acc[mi][ni][r];
            }
}

// ---------------- fp32 GEMM (kept for GEMM2 / GEMM3) ----------------
template<int EPI, int ATOMIC>
__global__ __launch_bounds__(256) void gemm64(
        const float* __restrict__ A, int lda,
        const float* __restrict__ B, int ldb,
        float* __restrict__ C, int ldc,
        int N, int K, const float* __restrict__ bias) {
    __shared__ float As[16][68];
    __shared__ float Bs[16][68];
    int m0 = blockIdx.x * 64;
    int n0 = blockIdx.y * 64;
    int tid = threadIdx.x;
    int tx = tid & 15, ty = tid >> 4;
    int arow = tid >> 2, acol = (tid & 3) * 4;
    int brow = tid >> 4, bcol = (tid & 15) * 4;

    int nk = K / 16 / gridDim.z;
    int kbase = blockIdx.z * nk * 16;

    const float* Aptr = A + (size_t)(m0 + arow) * lda + kbase + acol;
    const float* Bptr = B + (size_t)kbase * ldb + (size_t)brow * ldb;

    auto loadB = [&](int kt) -> float4 {
        const float* bp = Bptr + (size_t)kt * 16 * ldb;
        if (n0 + bcol + 4 <= N) {
            return *(const float4*)(bp + n0 + bcol);
        } else {
            float tmp[4] = {0.f, 0.f, 0.f, 0.f};
            #pragma unroll
            for (int j = 0; j < 4; j++)
                if (n0 + bcol + j < N) tmp[j] = bp[n0 + bcol + j];
            return make_float4(tmp[0], tmp[1], tmp[2], tmp[3]);
        }
    };

    float acc[4][4] = {};
    float4 av = *(const float4*)(Aptr);
    float4 bv = loadB(0);

    for (int kt = 0; kt < nk; kt++) {
        __syncthreads();
        As[acol + 0][arow] = av.x;
        As[acol + 1][arow] = av.y;
        As[acol + 2][arow] = av.z;
        As[acol + 3][arow] = av.w;
        *(float4*)&Bs[brow][bcol] = bv;
        __syncthreads();
        if (kt + 1 < nk) {
            av = *(const float4*)(Aptr + (kt + 1) * 16);
            bv = loadB(kt + 1);
        }
        #pragma unroll
        for (int k = 0; k < 16; k++) {
            float4 a4 = *(const float4*)&As[k][ty * 4];
            float4 b4 = *(const float4*)&Bs[k][tx * 4];
            float ar[4] = {a4.x, a4.y, a4.z, a4.w};
            float br[4] = {b4.x, b4.y, b4.z, b4.w};
            #pragma unroll
            for (int i = 0; i < 4; i++)
                #pragma unroll
                for (int j = 0; j < 4; j++)
                    acc[i][j] = fmaf(ar[i], br[j], acc[i][j]);
        }
    }
    #pragma unroll
    for (int i = 0; i < 4; i++) {
        int row = m0 + ty * 4 + i;
        #pragma unroll
        for (int j = 0; j < 4; j++) {
            int col = n0 + tx * 4 + j;
            if (col < N) {
                float v = acc[i][j];
                if (ATOMIC == 1) {
                    atomicAdd(&C[(size_t)row * ldc + col], v);
                } else {
                    if (EPI == 1) {
                        float u = v + bias[col];
                        v = (u > 15.f) ? u : log1pf(__expf(u));
                    }
                    C[(size_t)row * ldc + col] = v;
                }
            }
        }
    }
}

// ---------------- causal depthwise conv(4) + SiLU ----------------
__global__ __launch_bounds__(256) void conv_silu_kernel(const float* __restrict__ xz,
        const float* __restrict__ cw, const float* __restrict__ cb,
        float* __restrict__ xc) {
    int idx = blockIdx.x * 256 + threadIdx.x;
    int t = idx / D_INNER;
    int d = idx - t * D_INNER;
    float acc = cb[d];
    #pragma unroll
    for (int k = 0; k < 4; k++) {
        int ts = t - 3 + k;
        if (ts >= 0) acc = fmaf(xz[(size_t)ts * NXZ + d], cw[d * 4 + k], acc);
    }
    xc[idx] = acc / (1.f + __expf(-acc));
}

// ================= chunked selective scan =================
// S1: local scan (h0=0) per (d,chunk); emit final local h and chunk dt-sum.
__global__ __launch_bounds__(256) void scan_s1(
        const float* __restrict__ dtb, const float* __restrict__ xc,
        const float* __restrict__ dbl, const float* __restrict__ A_log,
        float* __restrict__ hloc, float* __restrict__ sdt) {
    int wid = threadIdx.x >> 6, lane = threadIdx.x & 63;
    int d = blockIdx.x * 4 + wid;
    int c = blockIdx.y;
    float An = -__expf(A_log[d * D_STATE + lane]);
    float h = 0.f, sdtv = 0.f;
    int tbase = c * QCH;
    #pragma unroll 8
    for (int i = 0; i < QCH; i++) {
        int t = tbase + i;
        float dtv = dtb[(size_t)t * D_INNER + d];
        float xcv = xc[(size_t)t * D_INNER + d];
        float Bv  = dbl[(size_t)t * NDBL + DT_RANK + lane];
        float a = __expf(dtv * An);
        h = fmaf(a, h, dtv * Bv * xcv);
        sdtv += dtv;
    }
    hloc[(c * D_INNER + d) * D_STATE + lane] = h;
    if (lane == 0) sdt[c * D_INNER + d] = sdtv;
}

// S2: per (d,n) thread: combine chunks; Pfac reconstructed from sdt in closed form.
__global__ __launch_bounds__(256) void scan_s2(
        const float* __restrict__ hloc, const float* __restrict__ sdt,
        const float* __restrict__ A_log, float* __restrict__ Hinit) {
    int idx = blockIdx.x * 256 + threadIdx.x;   // d*64 + n
    int d = idx >> 6;
    float An = -__expf(A_log[idx]);
    float H = 0.f;
    #pragma unroll
    for (int c = 0; c < NCHUNK; c++) {
        int o = c * (D_INNER * D_STATE) + idx;
        Hinit[o] = H;
        H = fmaf(__expf(sdt[c * D_INNER + d] * An), H, hloc[o]);
    }
}

// S3: seeded local scan + 10-shuffle fold reduction; epilogue writes bf16 y.
__global__ __launch_bounds__(256) void scan_s3(
        const float* __restrict__ dtb, const float* __restrict__ xc,
        const float* __restrict__ dbl, const float* __restrict__ A_log,
        const float* __restrict__ Hinit, const float* __restrict__ D_skip,
        const float* __restrict__ xz, unsigned short* __restrict__ yb) {
    int wid = threadIdx.x >> 6, lane = threadIdx.x & 63;
    int d = blockIdx.x * 4 + wid;
    int c = blockIdx.y;
    float An = -__expf(A_log[d * D_STATE + lane]);
    float Dv = D_skip[d];
    float h = Hinit[(c * D_INNER + d) * D_STATE + lane];
    int li = lane & 7;
    int tbase = c * QCH;
    for (int t0 = tbase; t0 < tbase + QCH; t0 += 8) {
        float p[8], dts[8], xcs[8];
        #pragma unroll
        for (int i = 0; i < 8; i++) {
            dts[i] = dtb[(size_t)(t0 + i) * D_INNER + d];
            xcs[i] = xc[(size_t)(t0 + i) * D_INNER + d];
        }
        #pragma unroll
        for (int i = 0; i < 8; i++) {
            int t = t0 + i;
            float Bv = dbl[(size_t)t * NDBL + DT_RANK + lane];
            float Cv = dbl[(size_t)t * NDBL + DT_RANK + D_STATE + lane];
            float a = __expf(dts[i] * An);
            h = fmaf(a, h, dts[i] * Bv * xcs[i]);
            p[i] = h * Cv;
        }
        float q[4];
        #pragma unroll
        for (int i = 0; i < 4; i++) {
            bool bb = (lane & 1) != 0;
            float send = bb ? p[2*i] : p[2*i+1];
            float keep = bb ? p[2*i+1] : p[2*i];
            q[i] = keep + __shfl_xor(send, 1, 64);
        }
        float r[2];
        #pragma unroll
        for (int i = 0; i < 2; i++) {
            bool bb = (lane & 2) != 0;
            float send = bb ? q[2*i] : q[2*i+1];
            float keep = bb ? q[2*i+1] : q[2*i];
            r[i] = keep + __shfl_xor(send, 2, 64);
        }
        float s;
        {
            bool bb = (lane & 4) != 0;
            float send = bb ? r[0] : r[1];
            float keep = bb ? r[1] : r[0];
            s = keep + __shfl_xor(send, 4, 64);
        }
        s += __shfl_xor(s, 8, 64);
        s += __shfl_xor(s, 16, 64);
        s += __shfl_xor(s, 32, 64);
        if (lane < 8) {
            int t = t0 + li;
            float xcv = xc[(size_t)t * D_INNER + d];
            float zv  = xz[(size_t)t * NXZ + D_INNER + d];
            float yv  = s + xcv * Dv;
            yb[(size_t)t * D_INNER + d] = bf_hi_u(yv * (zv / (1.f + __expf(-zv))));
        }
    }
}

// ---------------- host ----------------
extern "C" void kernel_launch(void* const* d_in, const int* in_sizes, int n_in,
                              void* d_out, int out_size, void* d_ws, size_t ws_size,
                              hipStream_t stream) {
    const float* x      = (const float*)d_in[0];
    const float* ln_g   = (const float*)d_in[1];
    const float* ln_b   = (const float*)d_in[2];
    const float* W_in   = (const float*)d_in[3];
    const float* conv_w = (const float*)d_in[4];
    const float* conv_b = (const float*)d_in[5];
    const float* W_x    = (const float*)d_in[6];
    const float* W_dt   = (const float*)d_in[7];
    const float* b_dt   = (const float*)d_in[8];
    const float* A_log  = (const float*)d_in[9];
    const float* D_skip = (const float*)d_in[10];
    const float* W_out  = (const float*)d_in[11];

    float* ws   = (float*)d_ws;
    float* xz   = ws;                  // 3145728
    float* xc   = ws + 3145728;        // 1572864
    float* dbl  = ws + 4718592;        // 180224
    float* dtb  = ws + 4898816;        // 1572864
    float* hloc = ws + 6471680;        // 1572864
    float* Hini = ws + 8044544;        // 1572864
    float* sdt  = ws + 9617408;        // 24576
    unsigned short* ubase     = (unsigned short*)(ws + 9641984);
    unsigned short* xn_hi     = ubase;              // 786432
    unsigned short* xn_lo     = ubase + 786432;     // 786432
    unsigned short* yv_b      = ubase;              // 1572864 (aliases xn planes; disjoint lifetime)
    unsigned short* Wt_in_hi  = ubase + 1572864;    // 2359296
    unsigned short* Wt_in_lo  = ubase + 3932160;    // 2359296
    unsigned short* Wt_out_hi = ubase + 6291456;    // 1179648  (total 53.5 MB)

    // zero split-K atomic targets
    hipMemsetAsync(dbl, 0, (size_t)L_SEQ * NDBL * sizeof(float), stream);
    hipMemsetAsync(d_out, 0, (size_t)L_SEQ * D_MODEL * sizeof(float), stream);

    // weight transpose+convert: W_in [768][3072] -> [3072][768] hi/lo; W_out [1536][768] -> [768][1536] hi
    tconv_kernel<1><<<dim3(NXZ / 32, D_MODEL / 32), 256, 0, stream>>>(W_in, D_MODEL, NXZ, Wt_in_hi, Wt_in_lo);
    tconv_kernel<0><<<dim3(D_MODEL / 32, D_INNER / 32), 256, 0, stream>>>(W_out, D_INNER, D_MODEL, Wt_out_hi, nullptr);

    ln_kernel<<<L_SEQ, 256, 0, stream>>>(x, ln_g, ln_b, xn_hi, xn_lo);
    // GEMM1: xz = xn @ W_in  (1024x3072, K=768) — split-bf16 x3 MFMA
    mgemm<1, 0><<<dim3(16, 48, 1), 256, 0, stream>>>(xn_hi, xn_lo, Wt_in_hi, Wt_in_lo, xz, NXZ, D_MODEL);
    conv_silu_kernel<<<(L_SEQ * D_INNER) / 256, 256, 0, stream>>>(xz, conv_w, conv_b, xc);
    // GEMM2: dbl += xc @ W_x  (1024x176, K=1536) — fp32 split-K x8
    gemm64<0, 1><<<dim3(16, 3, 8), 256, 0, stream>>>(xc, D_INNER, W_x, NDBL, dbl, NDBL, NDBL, D_INNER, nullptr);
    // GEMM3: dt = softplus(dt_raw @ W_dt + b_dt)  (1024x1536, K=48) — fp32
    gemm64<1, 0><<<dim3(16, 24, 1), 256, 0, stream>>>(dbl, NDBL, W_dt, D_INNER, dtb, D_INNER, D_INNER, DT_RANK, b_dt);
    scan_s1<<<dim3(D_INNER / 4, NCHUNK), 256, 0, stream>>>(dtb, xc, dbl, A_log, hloc, sdt);
    scan_s2<<<(D_INNER * D_STATE) / 256, 256, 0, stream>>>(hloc, sdt, A_log, Hini);
    scan_s3<<<dim3(D_INNER / 4, NCHUNK), 256, 0, stream>>>(dtb, xc, dbl, A_log, Hini, D_skip, xz, yv_b);
    // GEMM4: out += y @ W_out  (1024x768, K=1536) — plain bf16 MFMA, split-K x4
    mgemm<0, 1><<<dim3(16, 12, 4), 256, 0, stream>>>(yv_b, nullptr, Wt_out_hi, nullptr, (float*)d_out, D_MODEL, D_INNER);
}

// Round 5
// 308.855 us; speedup vs baseline: 1.9260x; 1.1829x over previous
//
#include <hip/hip_runtime.h>
#include <hip/hip_bf16.h>
#include <math.h>

#define D_MODEL 768
#define D_INNER 1536
#define L_SEQ   1024
#define DT_RANK 48
#define D_STATE 64
#define NXZ     3072   // 2*D_INNER
#define NDBL    176    // DT_RANK + 2*D_STATE
#define NCHUNK  16
#define QCH     64     // chunk length

typedef short  bfrag8 __attribute__((ext_vector_type(8)));
typedef float  f32x4  __attribute__((ext_vector_type(4)));

__device__ inline unsigned short bf_hi_u(float v) {
    __hip_bfloat16 h = __float2bfloat16(v);
    return *reinterpret_cast<unsigned short*>(&h);
}
__device__ inline float bf_to_f(unsigned short u) {
    __hip_bfloat16 h = *reinterpret_cast<__hip_bfloat16*>(&u);
    return __bfloat162float(h);
}

// ---------------- transpose + bf16(hi[,lo]) convert: src[R][C] fp32 -> dst[C][R] ----------------
template<int SPLIT>
__global__ __launch_bounds__(256) void tconv_kernel(const float* __restrict__ src, int R, int C,
        unsigned short* __restrict__ dhi, unsigned short* __restrict__ dlo) {
    __shared__ float tile[32][33];
    int tx = threadIdx.x & 31, ty = threadIdx.x >> 5;
    int c0 = blockIdx.x * 32, r0 = blockIdx.y * 32;
    #pragma unroll
    for (int i = 0; i < 4; i++)
        tile[ty + 8*i][tx] = src[(size_t)(r0 + ty + 8*i) * C + c0 + tx];
    __syncthreads();
    #pragma unroll
    for (int i = 0; i < 4; i++) {
        float v = tile[tx][ty + 8*i];
        size_t o = (size_t)(c0 + ty + 8*i) * R + r0 + tx;
        unsigned short h = bf_hi_u(v);
        dhi[o] = h;
        if (SPLIT) dlo[o] = bf_hi_u(v - bf_to_f(h));
    }
}

// ---------------- LayerNorm -> bf16 hi/lo planes ----------------
__global__ __launch_bounds__(256) void ln_kernel(const float* __restrict__ x,
        const float* __restrict__ g, const float* __restrict__ b,
        unsigned short* __restrict__ xn_hi, unsigned short* __restrict__ xn_lo) {
    int row = blockIdx.x;
    const float* xr = x + row * D_MODEL;
    float v[3];
    float s = 0.f, s2 = 0.f;
    #pragma unroll
    for (int i = 0; i < 3; i++) {
        v[i] = xr[threadIdx.x + i * 256];
        s += v[i]; s2 += v[i] * v[i];
    }
    #pragma unroll
    for (int o = 32; o > 0; o >>= 1) {
        s  += __shfl_xor(s,  o, 64);
        s2 += __shfl_xor(s2, o, 64);
    }
    __shared__ float red[2][4];
    int wid = threadIdx.x >> 6;
    if ((threadIdx.x & 63) == 0) { red[0][wid] = s; red[1][wid] = s2; }
    __syncthreads();
    s  = red[0][0] + red[0][1] + red[0][2] + red[0][3];
    s2 = red[1][0] + red[1][1] + red[1][2] + red[1][3];
    float mu  = s * (1.f / D_MODEL);
    float var = s2 * (1.f / D_MODEL) - mu * mu;
    float r   = rsqrtf(var + 1e-5f);
    #pragma unroll
    for (int i = 0; i < 3; i++) {
        int c = threadIdx.x + i * 256;
        float xv = (v[i] - mu) * r * g[c] + b[c];
        unsigned short h = bf_hi_u(xv);
        xn_hi[row * D_MODEL + c] = h;
        xn_lo[row * D_MODEL + c] = bf_hi_u(xv - bf_to_f(h));
    }
}

// ---------------- MFMA GEMM v2: C[M,N] (+)= A[M,K] * B^T[N,K] (bf16 planes) ----------------
// BM=BN=128, BK=32. 256 threads = 4 waves (2x2), each wave 64x64 = 4x4 of 16x16x32 tiles.
// LDS: unpadded [128][32] shorts with XOR swizzle (kgroup ^= 8*(row&3)):
//   stores conflict-free, frag reads 2-way (free). launch_bounds(256,2) -> 256-VGPR
//   budget, flat named prefetch regs: no scratch spill.
// SPLIT3: hi/lo planes, acc = hi*hi + hi*lo + lo*hi (~fp32). ATOMIC: split-K atomicAdd.
template<int SPLIT3, int ATOMIC>
__global__ __launch_bounds__(256, 2) void mgemm(
        const unsigned short* __restrict__ Ahi, const unsigned short* __restrict__ Alo,
        const unsigned short* __restrict__ Bhi, const unsigned short* __restrict__ Blo,
        float* __restrict__ C, int ldc, int K) {
    constexpr int NP = SPLIT3 ? 2 : 1;
    __shared__ unsigned short As[NP][128][32];
    __shared__ unsigned short Bs[NP][128][32];
    int tid = threadIdx.x;
    int m0 = blockIdx.x * 128, n0 = blockIdx.y * 128;
    int nk = K / 32 / gridDim.z;
    int kbase = blockIdx.z * nk * 32;

    // staging: 512 16B-segments per operand-plane, 2 per thread
    int ar0 = tid >> 1;                 // rows 0..127 (seg 0: tid even/odd -> 2 kgroups? no: idx scheme below)
    // use idx = tid + s*256: row = idx>>2, kgroup = (idx&3)*8
    int i0 = tid,        i1 = tid + 256;
    int r0i = i0 >> 2,   k0i = (i0 & 3) * 8;
    int r1i = i1 >> 2,   k1i = (i1 & 3) * 8;
    int sc0 = k0i ^ (8 * (r0i & 3));    // swizzled LDS col
    int sc1 = k1i ^ (8 * (r1i & 3));
    (void)ar0;

    const unsigned short* gA0h = Ahi + (size_t)(m0 + r0i) * K + kbase + k0i;
    const unsigned short* gA1h = Ahi + (size_t)(m0 + r1i) * K + kbase + k1i;
    const unsigned short* gB0h = Bhi + (size_t)(n0 + r0i) * K + kbase + k0i;
    const unsigned short* gB1h = Bhi + (size_t)(n0 + r1i) * K + kbase + k1i;
    const unsigned short* gA0l = SPLIT3 ? (Alo + (size_t)(m0 + r0i) * K + kbase + k0i) : nullptr;
    const unsigned short* gA1l = SPLIT3 ? (Alo + (size_t)(m0 + r1i) * K + kbase + k1i) : nullptr;
    const unsigned short* gB0l = SPLIT3 ? (Blo + (size_t)(n0 + r0i) * K + kbase + k0i) : nullptr;
    const unsigned short* gB1l = SPLIT3 ? (Blo + (size_t)(n0 + r1i) * K + kbase + k1i) : nullptr;

    uint4 va0h = *(const uint4*)gA0h, va1h = *(const uint4*)gA1h;
    uint4 vb0h = *(const uint4*)gB0h, vb1h = *(const uint4*)gB1h;
    uint4 va0l, va1l, vb0l, vb1l;
    if (SPLIT3) {
        va0l = *(const uint4*)gA0l; va1l = *(const uint4*)gA1l;
        vb0l = *(const uint4*)gB0l; vb1l = *(const uint4*)gB1l;
    }

    int wv = tid >> 6, L = tid & 63;
    int wr = (wv >> 1) * 64, wc = (wv & 1) * 64;
    int lm = L & 15, kq8 = (L >> 4) * 8;
    int rcol = kq8 ^ (8 * (L & 3));     // (row&3) == (lm&3) == (L&3) since tile bases %16==0

    f32x4 acc[4][4];
    #pragma unroll
    for (int i = 0; i < 4; i++)
        #pragma unroll
        for (int j = 0; j < 4; j++)
            #pragma unroll
            for (int r = 0; r < 4; r++) acc[i][j][r] = 0.f;

    for (int kt = 0; kt < nk; kt++) {
        __syncthreads();
        *(uint4*)&As[0][r0i][sc0] = va0h;
        *(uint4*)&As[0][r1i][sc1] = va1h;
        *(uint4*)&Bs[0][r0i][sc0] = vb0h;
        *(uint4*)&Bs[0][r1i][sc1] = vb1h;
        if (SPLIT3) {
            *(uint4*)&As[1][r0i][sc0] = va0l;
            *(uint4*)&As[1][r1i][sc1] = va1l;
            *(uint4*)&Bs[1][r0i][sc0] = vb0l;
            *(uint4*)&Bs[1][r1i][sc1] = vb1l;
        }
        __syncthreads();
        if (kt + 1 < nk) {             // prefetch next K-tile under the MFMAs
            int o = (kt + 1) * 32;
            va0h = *(const uint4*)(gA0h + o); va1h = *(const uint4*)(gA1h + o);
            vb0h = *(const uint4*)(gB0h + o); vb1h = *(const uint4*)(gB1h + o);
            if (SPLIT3) {
                va0l = *(const uint4*)(gA0l + o); va1l = *(const uint4*)(gA1l + o);
                vb0l = *(const uint4*)(gB0l + o); vb1l = *(const uint4*)(gB1l + o);
            }
        }
        bfrag8 fah[4], fal[4];
        #pragma unroll
        for (int mi = 0; mi < 4; mi++) {
            fah[mi] = *(const bfrag8*)&As[0][wr + mi * 16 + lm][rcol];
            if (SPLIT3) fal[mi] = *(const bfrag8*)&As[1][wr + mi * 16 + lm][rcol];
        }
        #pragma unroll
        for (int ni = 0; ni < 4; ni++) {
            bfrag8 fbh = *(const bfrag8*)&Bs[0][wc + ni * 16 + lm][rcol];
            #pragma unroll
            for (int mi = 0; mi < 4; mi++)
                acc[mi][ni] = __builtin_amdgcn_mfma_f32_16x16x32_bf16(fah[mi], fbh, acc[mi][ni], 0, 0, 0);
            if (SPLIT3) {
                bfrag8 fbl = *(const bfrag8*)&Bs[1][wc + ni * 16 + lm][rcol];
                #pragma unroll
                for (int mi = 0; mi < 4; mi++) {
                    acc[mi][ni] = __builtin_amdgcn_mfma_f32_16x16x32_bf16(fah[mi], fbl, acc[mi][ni], 0, 0, 0);
                    acc[mi][ni] = __builtin_amdgcn_mfma_f32_16x16x32_bf16(fal[mi], fbh, acc[mi][ni], 0, 0, 0);
                }
            }
        }
    }
    // C/D layout: col = lane&15, row = (lane>>4)*4 + reg
    int rbase = (L >> 4) * 4, cbase = L & 15;
    #pragma unroll
    for (int mi = 0; mi < 4; mi++)
        #pragma unroll
        for (int ni = 0; ni < 4; ni++)
            #pragma unroll
            for (int r = 0; r < 4; r++) {
                int rr = m0 + wr + mi * 16 + rbase + r;
                int cc = n0 + wc + ni * 16 + cbase;
                if (ATOMIC) atomicAdd(&C[(size_t)rr * ldc + cc], acc[mi][ni][r]);
                else        C[(size_t)rr * ldc + cc] = acc[mi][ni][r];
            }
}

// ---------------- fp32 GEMM (GEMM2 / GEMM3) ----------------
template<int EPI, int ATOMIC>
__global__ __launch_bounds__(256) void gemm64(
        const float* __restrict__ A, int lda,
        const float* __restrict__ B, int ldb,
        float* __restrict__ C, int ldc,
        int N, int K, const float* __restrict__ bias) {
    __shared__ float As[16][68];
    __shared__ float Bs[16][68];
    int m0 = blockIdx.x * 64;
    int n0 = blockIdx.y * 64;
    int tid = threadIdx.x;
    int tx = tid & 15, ty = tid >> 4;
    int arow = tid >> 2, acol = (tid & 3) * 4;
    int brow = tid >> 4, bcol = (tid & 15) * 4;

    int nk = K / 16 / gridDim.z;
    int kbase = blockIdx.z * nk * 16;

    const float* Aptr = A + (size_t)(m0 + arow) * lda + kbase + acol;
    const float* Bptr = B + (size_t)kbase * ldb + (size_t)brow * ldb;

    auto loadB = [&](int kt) -> float4 {
        const float* bp = Bptr + (size_t)kt * 16 * ldb;
        if (n0 + bcol + 4 <= N) {
            return *(const float4*)(bp + n0 + bcol);
        } else {
            float tmp[4] = {0.f, 0.f, 0.f, 0.f};
            #pragma unroll
            for (int j = 0; j < 4; j++)
                if (n0 + bcol + j < N) tmp[j] = bp[n0 + bcol + j];
            return make_float4(tmp[0], tmp[1], tmp[2], tmp[3]);
        }
    };

    float acc[4][4] = {};
    float4 av = *(const float4*)(Aptr);
    float4 bv = loadB(0);

    for (int kt = 0; kt < nk; kt++) {
        __syncthreads();
        As[acol + 0][arow] = av.x;
        As[acol + 1][arow] = av.y;
        As[acol + 2][arow] = av.z;
        As[acol + 3][arow] = av.w;
        *(float4*)&Bs[brow][bcol] = bv;
        __syncthreads();
        if (kt + 1 < nk) {
            av = *(const float4*)(Aptr + (kt + 1) * 16);
            bv = loadB(kt + 1);
        }
        #pragma unroll
        for (int k = 0; k < 16; k++) {
            float4 a4 = *(const float4*)&As[k][ty * 4];
            float4 b4 = *(const float4*)&Bs[k][tx * 4];
            float ar[4] = {a4.x, a4.y, a4.z, a4.w};
            float br[4] = {b4.x, b4.y, b4.z, b4.w};
            #pragma unroll
            for (int i = 0; i < 4; i++)
                #pragma unroll
                for (int j = 0; j < 4; j++)
                    acc[i][j] = fmaf(ar[i], br[j], acc[i][j]);
        }
    }
    #pragma unroll
    for (int i = 0; i < 4; i++) {
        int row = m0 + ty * 4 + i;
        #pragma unroll
        for (int j = 0; j < 4; j++) {
            int col = n0 + tx * 4 + j;
            if (col < N) {
                float v = acc[i][j];
                if (ATOMIC == 1) {
                    atomicAdd(&C[(size_t)row * ldc + col], v);
                } else {
                    if (EPI == 1) {
                        float u = v + bias[col];
                        v = (u > 15.f) ? u : log1pf(__expf(u));
                    }
                    C[(size_t)row * ldc + col] = v;
                }
            }
        }
    }
}

// ---------------- causal depthwise conv(4) + SiLU ----------------
__global__ __launch_bounds__(256) void conv_silu_kernel(const float* __restrict__ xz,
        const float* __restrict__ cw, const float* __restrict__ cb,
        float* __restrict__ xc) {
    int idx = blockIdx.x * 256 + threadIdx.x;
    int t = idx / D_INNER;
    int d = idx - t * D_INNER;
    float acc = cb[d];
    #pragma unroll
    for (int k = 0; k < 4; k++) {
        int ts = t - 3 + k;
        if (ts >= 0) acc = fmaf(xz[(size_t)ts * NXZ + d], cw[d * 4 + k], acc);
    }
    xc[idx] = acc / (1.f + __expf(-acc));
}

// ================= chunked selective scan =================
__global__ __launch_bounds__(256) void scan_s1(
        const float* __restrict__ dtb, const float* __restrict__ xc,
        const float* __restrict__ dbl, const float* __restrict__ A_log,
        float* __restrict__ hloc, float* __restrict__ sdt) {
    int wid = threadIdx.x >> 6, lane = threadIdx.x & 63;
    int d = blockIdx.x * 4 + wid;
    int c = blockIdx.y;
    float An = -__expf(A_log[d * D_STATE + lane]);
    float h = 0.f, sdtv = 0.f;
    int tbase = c * QCH;
    #pragma unroll 8
    for (int i = 0; i < QCH; i++) {
        int t = tbase + i;
        float dtv = dtb[(size_t)t * D_INNER + d];
        float xcv = xc[(size_t)t * D_INNER + d];
        float Bv  = dbl[(size_t)t * NDBL + DT_RANK + lane];
        float a = __expf(dtv * An);
        h = fmaf(a, h, dtv * Bv * xcv);
        sdtv += dtv;
    }
    hloc[(c * D_INNER + d) * D_STATE + lane] = h;
    if (lane == 0) sdt[c * D_INNER + d] = sdtv;
}

__global__ __launch_bounds__(256) void scan_s2(
        const float* __restrict__ hloc, const float* __restrict__ sdt,
        const float* __restrict__ A_log, float* __restrict__ Hinit) {
    int idx = blockIdx.x * 256 + threadIdx.x;   // d*64 + n
    int d = idx >> 6;
    float An = -__expf(A_log[idx]);
    float H = 0.f;
    #pragma unroll
    for (int c = 0; c < NCHUNK; c++) {
        int o = c * (D_INNER * D_STATE) + idx;
        Hinit[o] = H;
        H = fmaf(__expf(sdt[c * D_INNER + d] * An), H, hloc[o]);
    }
}

__global__ __launch_bounds__(256) void scan_s3(
        const float* __restrict__ dtb, const float* __restrict__ xc,
        const float* __restrict__ dbl, const float* __restrict__ A_log,
        const float* __restrict__ Hinit, const float* __restrict__ D_skip,
        const float* __restrict__ xz, unsigned short* __restrict__ yb) {
    int wid = threadIdx.x >> 6, lane = threadIdx.x & 63;
    int d = blockIdx.x * 4 + wid;
    int c = blockIdx.y;
    float An = -__expf(A_log[d * D_STATE + lane]);
    float Dv = D_skip[d];
    float h = Hinit[(c * D_INNER + d) * D_STATE + lane];
    int li = lane & 7;
    int tbase = c * QCH;
    for (int t0 = tbase; t0 < tbase + QCH; t0 += 8) {
        float p[8], dts[8], xcs[8];
        #pragma unroll
        for (int i = 0; i < 8; i++) {
            dts[i] = dtb[(size_t)(t0 + i) * D_INNER + d];
            xcs[i] = xc[(size_t)(t0 + i) * D_INNER + d];
        }
        #pragma unroll
        for (int i = 0; i < 8; i++) {
            int t = t0 + i;
            float Bv = dbl[(size_t)t * NDBL + DT_RANK + lane];
            float Cv = dbl[(size_t)t * NDBL + DT_RANK + D_STATE + lane];
            float a = __expf(dts[i] * An);
            h = fmaf(a, h, dts[i] * Bv * xcs[i]);
            p[i] = h * Cv;
        }
        float q[4];
        #pragma unroll
        for (int i = 0; i < 4; i++) {
            bool bb = (lane & 1) != 0;
            float send = bb ? p[2*i] : p[2*i+1];
            float keep = bb ? p[2*i+1] : p[2*i];
            q[i] = keep + __shfl_xor(send, 1, 64);
        }
        float r[2];
        #pragma unroll
        for (int i = 0; i < 2; i++) {
            bool bb = (lane & 2) != 0;
            float send = bb ? q[2*i] : q[2*i+1];
            float keep = bb ? q[2*i+1] : q[2*i];
            r[i] = keep + __shfl_xor(send, 2, 64);
        }
        float s;
        {
            bool bb = (lane & 4) != 0;
            float send = bb ? r[0] : r[1];
            float keep = bb ? r[1] : r[0];
            s = keep + __shfl_xor(send, 4, 64);
        }
        s += __shfl_xor(s, 8, 64);
        s += __shfl_xor(s, 16, 64);
        s += __shfl_xor(s, 32, 64);
        if (lane < 8) {
            int t = t0 + li;
            float xcv = xc[(size_t)t * D_INNER + d];
            float zv  = xz[(size_t)t * NXZ + D_INNER + d];
            float yv  = s + xcv * Dv;
            yb[(size_t)t * D_INNER + d] = bf_hi_u(yv * (zv / (1.f + __expf(-zv))));
        }
    }
}

// ---------------- host ----------------
extern "C" void kernel_launch(void* const* d_in, const int* in_sizes, int n_in,
                              void* d_out, int out_size, void* d_ws, size_t ws_size,
                              hipStream_t stream) {
    const float* x      = (const float*)d_in[0];
    const float* ln_g   = (const float*)d_in[1];
    const float* ln_b   = (const float*)d_in[2];
    const float* W_in   = (const float*)d_in[3];
    const float* conv_w = (const float*)d_in[4];
    const float* conv_b = (const float*)d_in[5];
    const float* W_x    = (const float*)d_in[6];
    const float* W_dt   = (const float*)d_in[7];
    const float* b_dt   = (const float*)d_in[8];
    const float* A_log  = (const float*)d_in[9];
    const float* D_skip = (const float*)d_in[10];
    const float* W_out  = (const float*)d_in[11];

    float* ws   = (float*)d_ws;
    float* xz   = ws;                  // 3145728
    float* xc   = ws + 3145728;        // 1572864
    float* dbl  = ws + 4718592;        // 180224
    float* dtb  = ws + 4898816;        // 1572864
    float* hloc = ws + 6471680;        // 1572864
    float* Hini = ws + 8044544;        // 1572864
    float* sdt  = ws + 9617408;        // 24576
    unsigned short* ubase     = (unsigned short*)(ws + 9641984);
    unsigned short* xn_hi     = ubase;              // 786432
    unsigned short* xn_lo     = ubase + 786432;     // 786432
    unsigned short* yv_b      = ubase;              // 1572864 (aliases xn planes; disjoint lifetime)
    unsigned short* Wt_in_hi  = ubase + 1572864;    // 2359296
    unsigned short* Wt_in_lo  = ubase + 3932160;    // 2359296
    unsigned short* Wt_out_hi = ubase + 6291456;    // 1179648  (total 53.5 MB)

    // zero split-K atomic targets
    hipMemsetAsync(dbl, 0, (size_t)L_SEQ * NDBL * sizeof(float), stream);
    hipMemsetAsync(d_out, 0, (size_t)L_SEQ * D_MODEL * sizeof(float), stream);

    // weight transpose+convert
    tconv_kernel<1><<<dim3(NXZ / 32, D_MODEL / 32), 256, 0, stream>>>(W_in, D_MODEL, NXZ, Wt_in_hi, Wt_in_lo);
    tconv_kernel<0><<<dim3(D_MODEL / 32, D_INNER / 32), 256, 0, stream>>>(W_out, D_INNER, D_MODEL, Wt_out_hi, nullptr);

    ln_kernel<<<L_SEQ, 256, 0, stream>>>(x, ln_g, ln_b, xn_hi, xn_lo);
    // GEMM1: xz = xn @ W_in  (1024x3072, K=768) — split-bf16 x3 MFMA, 128-tiles
    mgemm<1, 0><<<dim3(8, 24, 1), 256, 0, stream>>>(xn_hi, xn_lo, Wt_in_hi, Wt_in_lo, xz, NXZ, D_MODEL);
    conv_silu_kernel<<<(L_SEQ * D_INNER) / 256, 256, 0, stream>>>(xz, conv_w, conv_b, xc);
    // GEMM2: dbl += xc @ W_x  (1024x176, K=1536) — fp32 split-K x8
    gemm64<0, 1><<<dim3(16, 3, 8), 256, 0, stream>>>(xc, D_INNER, W_x, NDBL, dbl, NDBL, NDBL, D_INNER, nullptr);
    // GEMM3: dt = softplus(dt_raw @ W_dt + b_dt)  (1024x1536, K=48) — fp32
    gemm64<1, 0><<<dim3(16, 24, 1), 256, 0, stream>>>(dbl, NDBL, W_dt, D_INNER, dtb, D_INNER, D_INNER, DT_RANK, b_dt);
    scan_s1<<<dim3(D_INNER / 4, NCHUNK), 256, 0, stream>>>(dtb, xc, dbl, A_log, hloc, sdt);
    scan_s2<<<(D_INNER * D_STATE) / 256, 256, 0, stream>>>(hloc, sdt, A_log, Hini);
    scan_s3<<<dim3(D_INNER / 4, NCHUNK), 256, 0, stream>>>(dtb, xc, dbl, A_log, Hini, D_skip, xz, yv_b);
    // GEMM4: out += y @ W_out  (1024x768, K=1536) — bf16 MFMA, 128-tiles, split-K x4
    mgemm<0, 1><<<dim3(8, 6, 4), 256, 0, stream>>>(yv_b, nullptr, Wt_out_hi, nullptr, (float*)d_out, D_MODEL, D_INNER);
}

// Round 6
// 281.870 us; speedup vs baseline: 2.1104x; 1.0957x over previous
//
#include <hip/hip_runtime.h>
#include <hip/hip_bf16.h>
#include <math.h>

#define D_MODEL 768
#define D_INNER 1536
#define L_SEQ   1024
#define DT_RANK 48
#define D_STATE 64
#define NXZ     3072   // 2*D_INNER
#define NDBL    176    // DT_RANK + 2*D_STATE
#define NCHUNK  16
#define QCH     64     // chunk length
#define LOG2E   1.4426950408889634f

typedef short  bfrag8 __attribute__((ext_vector_type(8)));
typedef float  f32x4  __attribute__((ext_vector_type(4)));

__device__ inline unsigned short bf_hi_u(float v) {
    __hip_bfloat16 h = __float2bfloat16(v);
    return *reinterpret_cast<unsigned short*>(&h);
}
__device__ inline float bf_to_f(unsigned short u) {
    __hip_bfloat16 h = *reinterpret_cast<__hip_bfloat16*>(&u);
    return __bfloat162float(h);
}

// ---------------- transpose + bf16(hi[,lo]) convert: src[R][C] fp32 -> dst[Cpad][R] ----------------
// grid.x covers Cpad/32 (may exceed C: writes zeros), grid.y = R/32. Guard on source col.
template<int SPLIT>
__global__ __launch_bounds__(256) void tconv_kernel(const float* __restrict__ src, int R, int C,
        int Cvalid, unsigned short* __restrict__ dhi, unsigned short* __restrict__ dlo) {
    __shared__ float tile[32][33];
    int tx = threadIdx.x & 31, ty = threadIdx.x >> 5;
    int c0 = blockIdx.x * 32, r0 = blockIdx.y * 32;
    #pragma unroll
    for (int i = 0; i < 4; i++) {
        int c = c0 + tx;
        tile[ty + 8*i][tx] = (c < Cvalid) ? src[(size_t)(r0 + ty + 8*i) * C + c] : 0.f;
    }
    __syncthreads();
    #pragma unroll
    for (int i = 0; i < 4; i++) {
        float v = tile[tx][ty + 8*i];
        size_t o = (size_t)(c0 + ty + 8*i) * R + r0 + tx;
        unsigned short h = bf_hi_u(v);
        dhi[o] = h;
        if (SPLIT) dlo[o] = bf_hi_u(v - bf_to_f(h));
    }
}

// ---------------- LayerNorm -> bf16 hi/lo planes ----------------
__global__ __launch_bounds__(256) void ln_kernel(const float* __restrict__ x,
        const float* __restrict__ g, const float* __restrict__ b,
        unsigned short* __restrict__ xn_hi, unsigned short* __restrict__ xn_lo) {
    int row = blockIdx.x;
    const float* xr = x + row * D_MODEL;
    float v[3];
    float s = 0.f, s2 = 0.f;
    #pragma unroll
    for (int i = 0; i < 3; i++) {
        v[i] = xr[threadIdx.x + i * 256];
        s += v[i]; s2 += v[i] * v[i];
    }
    #pragma unroll
    for (int o = 32; o > 0; o >>= 1) {
        s  += __shfl_xor(s,  o, 64);
        s2 += __shfl_xor(s2, o, 64);
    }
    __shared__ float red[2][4];
    int wid = threadIdx.x >> 6;
    if ((threadIdx.x & 63) == 0) { red[0][wid] = s; red[1][wid] = s2; }
    __syncthreads();
    s  = red[0][0] + red[0][1] + red[0][2] + red[0][3];
    s2 = red[1][0] + red[1][1] + red[1][2] + red[1][3];
    float mu  = s * (1.f / D_MODEL);
    float var = s2 * (1.f / D_MODEL) - mu * mu;
    float r   = rsqrtf(var + 1e-5f);
    #pragma unroll
    for (int i = 0; i < 3; i++) {
        int c = threadIdx.x + i * 256;
        float xv = (v[i] - mu) * r * g[c] + b[c];
        unsigned short h = bf_hi_u(xv);
        xn_hi[row * D_MODEL + c] = h;
        xn_lo[row * D_MODEL + c] = bf_hi_u(xv - bf_to_f(h));
    }
}

// ---------------- MFMA GEMM: C[M,N] (+)= A[M,K] * B^T[N,K] (bf16 planes) ----------------
// BM=BN=128, BK=32, 4 waves, XOR-swizzled LDS; nvalid guards the store columns.
template<int SPLIT3, int ATOMIC>
__global__ __launch_bounds__(256, 2) void mgemm(
        const unsigned short* __restrict__ Ahi, const unsigned short* __restrict__ Alo,
        const unsigned short* __restrict__ Bhi, const unsigned short* __restrict__ Blo,
        float* __restrict__ C, int ldc, int K, int nvalid) {
    constexpr int NP = SPLIT3 ? 2 : 1;
    __shared__ unsigned short As[NP][128][32];
    __shared__ unsigned short Bs[NP][128][32];
    int tid = threadIdx.x;
    int m0 = blockIdx.x * 128, n0 = blockIdx.y * 128;
    int nk = K / 32 / gridDim.z;
    int kbase = blockIdx.z * nk * 32;

    int i0 = tid,        i1 = tid + 256;
    int r0i = i0 >> 2,   k0i = (i0 & 3) * 8;
    int r1i = i1 >> 2,   k1i = (i1 & 3) * 8;
    int sc0 = k0i ^ (8 * (r0i & 3));
    int sc1 = k1i ^ (8 * (r1i & 3));

    const unsigned short* gA0h = Ahi + (size_t)(m0 + r0i) * K + kbase + k0i;
    const unsigned short* gA1h = Ahi + (size_t)(m0 + r1i) * K + kbase + k1i;
    const unsigned short* gB0h = Bhi + (size_t)(n0 + r0i) * K + kbase + k0i;
    const unsigned short* gB1h = Bhi + (size_t)(n0 + r1i) * K + kbase + k1i;
    const unsigned short* gA0l = SPLIT3 ? (Alo + (size_t)(m0 + r0i) * K + kbase + k0i) : nullptr;
    const unsigned short* gA1l = SPLIT3 ? (Alo + (size_t)(m0 + r1i) * K + kbase + k1i) : nullptr;
    const unsigned short* gB0l = SPLIT3 ? (Blo + (size_t)(n0 + r0i) * K + kbase + k0i) : nullptr;
    const unsigned short* gB1l = SPLIT3 ? (Blo + (size_t)(n0 + r1i) * K + kbase + k1i) : nullptr;

    uint4 va0h = *(const uint4*)gA0h, va1h = *(const uint4*)gA1h;
    uint4 vb0h = *(const uint4*)gB0h, vb1h = *(const uint4*)gB1h;
    uint4 va0l, va1l, vb0l, vb1l;
    if (SPLIT3) {
        va0l = *(const uint4*)gA0l; va1l = *(const uint4*)gA1l;
        vb0l = *(const uint4*)gB0l; vb1l = *(const uint4*)gB1l;
    }

    int wv = tid >> 6, L = tid & 63;
    int wr = (wv >> 1) * 64, wc = (wv & 1) * 64;
    int lm = L & 15, kq8 = (L >> 4) * 8;
    int rcol = kq8 ^ (8 * (L & 3));

    f32x4 acc[4][4];
    #pragma unroll
    for (int i = 0; i < 4; i++)
        #pragma unroll
        for (int j = 0; j < 4; j++)
            #pragma unroll
            for (int r = 0; r < 4; r++) acc[i][j][r] = 0.f;

    for (int kt = 0; kt < nk; kt++) {
        __syncthreads();
        *(uint4*)&As[0][r0i][sc0] = va0h;
        *(uint4*)&As[0][r1i][sc1] = va1h;
        *(uint4*)&Bs[0][r0i][sc0] = vb0h;
        *(uint4*)&Bs[0][r1i][sc1] = vb1h;
        if (SPLIT3) {
            *(uint4*)&As[1][r0i][sc0] = va0l;
            *(uint4*)&As[1][r1i][sc1] = va1l;
            *(uint4*)&Bs[1][r0i][sc0] = vb0l;
            *(uint4*)&Bs[1][r1i][sc1] = vb1l;
        }
        __syncthreads();
        if (kt + 1 < nk) {
            int o = (kt + 1) * 32;
            va0h = *(const uint4*)(gA0h + o); va1h = *(const uint4*)(gA1h + o);
            vb0h = *(const uint4*)(gB0h + o); vb1h = *(const uint4*)(gB1h + o);
            if (SPLIT3) {
                va0l = *(const uint4*)(gA0l + o); va1l = *(const uint4*)(gA1l + o);
                vb0l = *(const uint4*)(gB0l + o); vb1l = *(const uint4*)(gB1l + o);
            }
        }
        bfrag8 fah[4], fal[4];
        #pragma unroll
        for (int mi = 0; mi < 4; mi++) {
            fah[mi] = *(const bfrag8*)&As[0][wr + mi * 16 + lm][rcol];
            if (SPLIT3) fal[mi] = *(const bfrag8*)&As[1][wr + mi * 16 + lm][rcol];
        }
        #pragma unroll
        for (int ni = 0; ni < 4; ni++) {
            bfrag8 fbh = *(const bfrag8*)&Bs[0][wc + ni * 16 + lm][rcol];
            #pragma unroll
            for (int mi = 0; mi < 4; mi++)
                acc[mi][ni] = __builtin_amdgcn_mfma_f32_16x16x32_bf16(fah[mi], fbh, acc[mi][ni], 0, 0, 0);
            if (SPLIT3) {
                bfrag8 fbl = *(const bfrag8*)&Bs[1][wc + ni * 16 + lm][rcol];
                #pragma unroll
                for (int mi = 0; mi < 4; mi++) {
                    acc[mi][ni] = __builtin_amdgcn_mfma_f32_16x16x32_bf16(fah[mi], fbl, acc[mi][ni], 0, 0, 0);
                    acc[mi][ni] = __builtin_amdgcn_mfma_f32_16x16x32_bf16(fal[mi], fbh, acc[mi][ni], 0, 0, 0);
                }
            }
        }
    }
    int rbase = (L >> 4) * 4, cbase = L & 15;
    #pragma unroll
    for (int mi = 0; mi < 4; mi++)
        #pragma unroll
        for (int ni = 0; ni < 4; ni++) {
            int cc = n0 + wc + ni * 16 + cbase;
            if (cc < nvalid) {
                #pragma unroll
                for (int r = 0; r < 4; r++) {
                    int rr = m0 + wr + mi * 16 + rbase + r;
                    if (ATOMIC) atomicAdd(&C[(size_t)rr * ldc + cc], acc[mi][ni][r]);
                    else        C[(size_t)rr * ldc + cc] = acc[mi][ni][r];
                }
            }
        }
}

// ---------------- fp32 GEMM (GEMM3) ----------------
// TRANS==1: stores C^T (ldc = transposed leading dim, float4 over row-quad).
template<int EPI, int TRANS>
__global__ __launch_bounds__(256) void gemm64(
        const float* __restrict__ A, int lda,
        const float* __restrict__ B, int ldb,
        float* __restrict__ C, int ldc,
        int N, int K, const float* __restrict__ bias) {
    __shared__ float As[16][68];
    __shared__ float Bs[16][68];
    int m0 = blockIdx.x * 64;
    int n0 = blockIdx.y * 64;
    int tid = threadIdx.x;
    int tx = tid & 15, ty = tid >> 4;
    int arow = tid >> 2, acol = (tid & 3) * 4;
    int brow = tid >> 4, bcol = (tid & 15) * 4;

    int nk = K / 16;

    const float* Aptr = A + (size_t)(m0 + arow) * lda + acol;
    const float* Bptr = B + (size_t)brow * ldb;

    float acc[4][4] = {};
    float4 av = *(const float4*)(Aptr);
    float4 bv = *(const float4*)(Bptr + n0 + bcol);

    for (int kt = 0; kt < nk; kt++) {
        __syncthreads();
        As[acol + 0][arow] = av.x;
        As[acol + 1][arow] = av.y;
        As[acol + 2][arow] = av.z;
        As[acol + 3][arow] = av.w;
        *(float4*)&Bs[brow][bcol] = bv;
        __syncthreads();
        if (kt + 1 < nk) {
            av = *(const float4*)(Aptr + (kt + 1) * 16);
            bv = *(const float4*)(Bptr + (size_t)(kt + 1) * 16 * ldb + n0 + bcol);
        }
        #pragma unroll
        for (int k = 0; k < 16; k++) {
            float4 a4 = *(const float4*)&As[k][ty * 4];
            float4 b4 = *(const float4*)&Bs[k][tx * 4];
            float ar[4] = {a4.x, a4.y, a4.z, a4.w};
            float br[4] = {b4.x, b4.y, b4.z, b4.w};
            #pragma unroll
            for (int i = 0; i < 4; i++)
                #pragma unroll
                for (int j = 0; j < 4; j++)
                    acc[i][j] = fmaf(ar[i], br[j], acc[i][j]);
        }
    }
    if (TRANS) {
        #pragma unroll
        for (int j = 0; j < 4; j++) {
            int col = n0 + tx * 4 + j;
            float4 v4;
            float* vp = (float*)&v4;
            #pragma unroll
            for (int i = 0; i < 4; i++) {
                float v = acc[i][j];
                if (EPI == 1) {
                    float u = v + bias[col];
                    v = (u > 15.f) ? u : log1pf(__expf(u));
                }
                vp[i] = v;
            }
            *(float4*)&C[(size_t)col * ldc + m0 + ty * 4] = v4;
        }
    } else {
        #pragma unroll
        for (int i = 0; i < 4; i++) {
            int row = m0 + ty * 4 + i;
            #pragma unroll
            for (int j = 0; j < 4; j++) {
                int col = n0 + tx * 4 + j;
                float v = acc[i][j];
                if (EPI == 1) {
                    float u = v + bias[col];
                    v = (u > 15.f) ? u : log1pf(__expf(u));
                }
                C[(size_t)row * ldc + col] = v;
            }
        }
    }
}

// ---------------- causal depthwise conv(4) + SiLU, tiled ----------------
// Writes xc_t fp32 [d][t] (for scans) and xcb hi/lo bf16 [t][d] (for GEMM2 MFMA).
__global__ __launch_bounds__(256) void conv_t_kernel(const float* __restrict__ xz,
        const float* __restrict__ cw, const float* __restrict__ cb,
        float* __restrict__ xc_t, unsigned short* __restrict__ xcb_hi,
        unsigned short* __restrict__ xcb_lo) {
    __shared__ float tile[67][65];
    int d0 = blockIdx.x * 64, t0 = blockIdx.y * 64;
    int lane = threadIdx.x & 63, grp = threadIdx.x >> 6;
    #pragma unroll
    for (int p = 0; p < 17; p++) {
        int r = p * 4 + grp;
        if (r < 67) {
            int t = t0 - 3 + r;
            tile[r][lane] = (t >= 0) ? xz[(size_t)t * NXZ + d0 + lane] : 0.f;
        }
    }
    __syncthreads();
    // pass A: lanes vary t -> coalesced xc_t[d][t] store
    #pragma unroll
    for (int p = 0; p < 16; p++) {
        int dl = grp + p * 4;
        int d = d0 + dl;
        float acc = cb[d];
        #pragma unroll
        for (int k = 0; k < 4; k++) acc = fmaf(tile[lane + k][dl], cw[d * 4 + k], acc);
        float s = acc / (1.f + __expf(-acc));
        xc_t[(size_t)d * L_SEQ + t0 + lane] = s;
    }
    // pass B: lanes vary d -> coalesced xcb[t][d] stores
    #pragma unroll
    for (int p = 0; p < 16; p++) {
        int tl = grp + p * 4;
        int d = d0 + lane;
        float acc = cb[d];
        #pragma unroll
        for (int k = 0; k < 4; k++) acc = fmaf(tile[tl + k][lane], cw[d * 4 + k], acc);
        float s = acc / (1.f + __expf(-acc));
        unsigned short h = bf_hi_u(s);
        size_t o = (size_t)(t0 + tl) * D_INNER + d;
        xcb_hi[o] = h;
        xcb_lo[o] = bf_hi_u(s - bf_to_f(h));
    }
}

// ================= chunked selective scan (transposed dt/xc layouts) =================
__global__ __launch_bounds__(256) void scan_s1(
        const float* __restrict__ dt_t, const float* __restrict__ xc_t,
        const float* __restrict__ dbl, const float* __restrict__ A_log,
        float* __restrict__ hloc, float* __restrict__ sdt) {
    int wid = threadIdx.x >> 6, lane = threadIdx.x & 63;
    int d = blockIdx.x * 4 + wid;
    int c = blockIdx.y;
    float An2 = -__expf(A_log[d * D_STATE + lane]) * LOG2E;
    int tbase = c * QCH;
    const float4* pdt = (const float4*)(dt_t + (size_t)d * L_SEQ + tbase);
    const float4* pxc = (const float4*)(xc_t + (size_t)d * L_SEQ + tbase);
    const float* pB = dbl + (size_t)tbase * NDBL + DT_RANK + lane;
    float h = 0.f, sdtv = 0.f;
    #pragma unroll
    for (int g = 0; g < 8; g++) {
        float4 d0 = pdt[2*g], d1 = pdt[2*g+1];
        float4 x0 = pxc[2*g], x1 = pxc[2*g+1];
        float dts[8] = {d0.x, d0.y, d0.z, d0.w, d1.x, d1.y, d1.z, d1.w};
        float xcs[8] = {x0.x, x0.y, x0.z, x0.w, x1.x, x1.y, x1.z, x1.w};
        #pragma unroll
        for (int i = 0; i < 8; i++) {
            float Bv = pB[i * NDBL];
            float a = exp2f(dts[i] * An2);
            h = fmaf(a, h, (dts[i] * xcs[i]) * Bv);
            sdtv += dts[i];
        }
        pB += 8 * NDBL;
    }
    hloc[(c * D_INNER + d) * D_STATE + lane] = h;
    if (lane == 0) sdt[c * D_INNER + d] = sdtv;
}

__global__ __launch_bounds__(256) void scan_s2(
        const float* __restrict__ hloc, const float* __restrict__ sdt,
        const float* __restrict__ A_log, float* __restrict__ Hinit) {
    int idx = blockIdx.x * 256 + threadIdx.x;   // d*64 + n
    int d = idx >> 6;
    float An2 = -__expf(A_log[idx]) * LOG2E;
    float H = 0.f;
    #pragma unroll
    for (int c = 0; c < NCHUNK; c++) {
        int o = c * (D_INNER * D_STATE) + idx;
        Hinit[o] = H;
        H = fmaf(exp2f(sdt[c * D_INNER + d] * An2), H, hloc[o]);
    }
}

__global__ __launch_bounds__(256) void scan_s3(
        const float* __restrict__ dt_t, const float* __restrict__ xc_t,
        const float* __restrict__ dbl, const float* __restrict__ A_log,
        const float* __restrict__ Hinit, const float* __restrict__ D_skip,
        const float* __restrict__ xz, unsigned short* __restrict__ yb) {
    int wid = threadIdx.x >> 6, lane = threadIdx.x & 63;
    int d = blockIdx.x * 4 + wid;
    int c = blockIdx.y;
    float An2 = -__expf(A_log[d * D_STATE + lane]) * LOG2E;
    float Dv64 = D_skip[d] * (1.f / 64.f);
    float h = Hinit[(c * D_INNER + d) * D_STATE + lane];
    int li = lane & 7;
    int tbase = c * QCH;
    const float4* pdt = (const float4*)(dt_t + (size_t)d * L_SEQ + tbase);
    const float4* pxc = (const float4*)(xc_t + (size_t)d * L_SEQ + tbase);
    const float* pB = dbl + (size_t)tbase * NDBL + DT_RANK + lane;
    const float* pz = xz + (size_t)(tbase + li) * NXZ + D_INNER + d;   // only lanes<8 use
    unsigned short* py = yb + (size_t)(tbase + li) * D_INNER + d;
    #pragma unroll
    for (int g = 0; g < 8; g++) {
        float4 d0 = pdt[2*g], d1 = pdt[2*g+1];
        float4 x0 = pxc[2*g], x1 = pxc[2*g+1];
        float dts[8] = {d0.x, d0.y, d0.z, d0.w, d1.x, d1.y, d1.z, d1.w};
        float xcs[8] = {x0.x, x0.y, x0.z, x0.w, x1.x, x1.y, x1.z, x1.w};
        float p[8];
        #pragma unroll
        for (int i = 0; i < 8; i++) {
            float Bv = pB[i * NDBL];
            float Cv = pB[i * NDBL + D_STATE];
            float a = exp2f(dts[i] * An2);
            h = fmaf(a, h, (dts[i] * xcs[i]) * Bv);
            p[i] = fmaf(h, Cv, xcs[i] * Dv64);   // skip term folded: 64 lanes sum to xc*D
        }
        pB += 8 * NDBL;
        // fold network: 10 shuffles per 8 values; lane ends with full sum for idx (lane&7)
        float q[4];
        #pragma unroll
        for (int i = 0; i < 4; i++) {
            bool bb = (lane & 1) != 0;
            float send = bb ? p[2*i] : p[2*i+1];
            float keep = bb ? p[2*i+1] : p[2*i];
            q[i] = keep + __shfl_xor(send, 1, 64);
        }
        float r[2];
        #pragma unroll
        for (int i = 0; i < 2; i++) {
            bool bb = (lane & 2) != 0;
            float send = bb ? q[2*i] : q[2*i+1];
            float keep = bb ? q[2*i+1] : q[2*i];
            r[i] = keep + __shfl_xor(send, 2, 64);
        }
        float s;
        {
            bool bb = (lane & 4) != 0;
            float send = bb ? r[0] : r[1];
            float keep = bb ? r[1] : r[0];
            s = keep + __shfl_xor(send, 4, 64);
        }
        s += __shfl_xor(s, 8, 64);
        s += __shfl_xor(s, 16, 64);
        s += __shfl_xor(s, 32, 64);
        if (lane < 8) {
            float zv = *pz;
            *py = bf_hi_u(s * (zv / (1.f + __expf(-zv))));
        }
        pz += 8 * NXZ;
        py += 8 * D_INNER;
    }
}

// ---------------- host ----------------
extern "C" void kernel_launch(void* const* d_in, const int* in_sizes, int n_in,
                              void* d_out, int out_size, void* d_ws, size_t ws_size,
                              hipStream_t stream) {
    const float* x      = (const float*)d_in[0];
    const float* ln_g   = (const float*)d_in[1];
    const float* ln_b   = (const float*)d_in[2];
    const float* W_in   = (const float*)d_in[3];
    const float* conv_w = (const float*)d_in[4];
    const float* conv_b = (const float*)d_in[5];
    const float* W_x    = (const float*)d_in[6];
    const float* W_dt   = (const float*)d_in[7];
    const float* b_dt   = (const float*)d_in[8];
    const float* A_log  = (const float*)d_in[9];
    const float* D_skip = (const float*)d_in[10];
    const float* W_out  = (const float*)d_in[11];

    float* ws   = (float*)d_ws;
    float* xz   = ws;                  // 3145728
    float* xc_t = ws + 3145728;        // 1572864  [d][t]
    float* dbl  = ws + 4718592;        // 180224   [t][176]
    float* dt_t = ws + 4898816;        // 1572864  [d][t]
    float* hloc = ws + 6471680;        // 1572864
    float* Hini = ws + 8044544;        // 1572864
    float* sdt  = ws + 9617408;        // 24576
    unsigned short* ubase     = (unsigned short*)(ws + 9641984);
    unsigned short* xn_hi     = ubase;               // 786432
    unsigned short* xn_lo     = ubase + 786432;      // 786432
    unsigned short* yv_b      = ubase;               // 1572864 (aliases xn; disjoint lifetime)
    unsigned short* Wt_in_hi  = ubase + 1572864;     // 2359296
    unsigned short* Wt_in_lo  = ubase + 3932160;     // 2359296
    unsigned short* Wt_out_hi = ubase + 6291456;     // 1179648
    unsigned short* WxT_hi    = ubase + 7471104;     // 393216 (256 rows x 1536, padded)
    unsigned short* WxT_lo    = ubase + 7864320;     // 393216
    unsigned short* xcb_hi    = ubase + 8257536;     // 1572864  [t][d]
    unsigned short* xcb_lo    = ubase + 9830400;     // 1572864  (end 61.4 MB)

    // zero split-K atomic targets
    hipMemsetAsync(dbl, 0, (size_t)L_SEQ * NDBL * sizeof(float), stream);
    hipMemsetAsync(d_out, 0, (size_t)L_SEQ * D_MODEL * sizeof(float), stream);

    // weight transpose+convert
    tconv_kernel<1><<<dim3(NXZ / 32, D_MODEL / 32), 256, 0, stream>>>(W_in, D_MODEL, NXZ, NXZ, Wt_in_hi, Wt_in_lo);
    tconv_kernel<0><<<dim3(D_MODEL / 32, D_INNER / 32), 256, 0, stream>>>(W_out, D_INNER, D_MODEL, D_MODEL, Wt_out_hi, nullptr);
    tconv_kernel<1><<<dim3(256 / 32, D_INNER / 32), 256, 0, stream>>>(W_x, D_INNER, NDBL, NDBL, WxT_hi, WxT_lo);

    ln_kernel<<<L_SEQ, 256, 0, stream>>>(x, ln_g, ln_b, xn_hi, xn_lo);
    // GEMM1: xz = xn @ W_in  (1024x3072, K=768) — split-bf16 x3 MFMA
    mgemm<1, 0><<<dim3(8, 24, 1), 256, 0, stream>>>(xn_hi, xn_lo, Wt_in_hi, Wt_in_lo, xz, NXZ, D_MODEL, NXZ);
    // conv + silu: xc_t fp32 [d][t] + xcb bf16 hi/lo [t][d]
    conv_t_kernel<<<dim3(D_INNER / 64, L_SEQ / 64), 256, 0, stream>>>(xz, conv_w, conv_b, xc_t, xcb_hi, xcb_lo);
    // GEMM2: dbl += xc @ W_x  (1024x176, K=1536) — split-bf16 x3 MFMA, split-K x4
    mgemm<1, 1><<<dim3(8, 2, 4), 256, 0, stream>>>(xcb_hi, xcb_lo, WxT_hi, WxT_lo, dbl, NDBL, D_INNER, NDBL);
    // GEMM3: dt_t = softplus(dt_raw @ W_dt + b_dt)^T  (transposed store [d][t])
    gemm64<1, 1><<<dim3(16, 24, 1), 256, 0, stream>>>(dbl, NDBL, W_dt, D_INNER, dt_t, L_SEQ, D_INNER, DT_RANK, b_dt);
    scan_s1<<<dim3(D_INNER / 4, NCHUNK), 256, 0, stream>>>(dt_t, xc_t, dbl, A_log, hloc, sdt);
    scan_s2<<<(D_INNER * D_STATE) / 256, 256, 0, stream>>>(hloc, sdt, A_log, Hini);
    scan_s3<<<dim3(D_INNER / 4, NCHUNK), 256, 0, stream>>>(dt_t, xc_t, dbl, A_log, Hini, D_skip, xz, yv_b);
    // GEMM4: out += y @ W_out  (1024x768, K=1536) — bf16 MFMA, split-K x4
    mgemm<0, 1><<<dim3(8, 6, 4), 256, 0, stream>>>(yv_b, nullptr, Wt_out_hi, nullptr, (float*)d_out, D_MODEL, D_INNER, D_MODEL);
}